// Round 1
// baseline (209.233 us; speedup 1.0000x reference)
//
#include <hip/hip_runtime.h>
#include <cstdint>
#include <cstddef>

#define D_MODEL 1024
#define D_STATE 16
#define D_CONV  4
#define D_INNER 2048
#define SEQ     2048
#define NCHUNK  64
#define CLEN    32
#define LN_EPS  1e-5f

typedef unsigned short ushort_t;
typedef __attribute__((ext_vector_type(8))) short short8;
typedef __attribute__((ext_vector_type(4))) float f32x4;

__device__ __forceinline__ ushort_t f2bf(float x) {
  union { float f; uint32_t u; } v; v.f = x;
  uint32_t r = (v.u + 0x7fffu + ((v.u >> 16) & 1u)) >> 16;
  return (ushort_t)r;
}

__device__ __forceinline__ void async16(void* lds, const void* g) {
  __builtin_amdgcn_global_load_lds(
      (const __attribute__((address_space(1))) unsigned int*)g,
      (__attribute__((address_space(3))) unsigned int*)lds, 16, 0, 0);
}

// ---------------- weight conversion (f32 -> bf16) ----------------
__global__ void cvt_w_kernel(const float* __restrict__ inw,
                             const float* __restrict__ outw,
                             ushort_t* __restrict__ inw_bf,
                             ushort_t* __restrict__ outw_bf) {
  int idx = blockIdx.x * 256 + threadIdx.x;
  const int n1 = 2 * D_INNER * D_MODEL;   // 4096*1024
  const int n2 = D_MODEL * D_INNER;       // 1024*2048
  if (idx < n1) {
    inw_bf[idx] = f2bf(inw[idx]);
  } else {
    int j = idx - n1;
    if (j < n2) outw_bf[j] = f2bf(outw[j]);
  }
}

// ---------------- LayerNorm -> bf16 ----------------
__global__ __launch_bounds__(256) void ln_kernel(const float* __restrict__ x,
                                                 const float* __restrict__ g,
                                                 const float* __restrict__ b,
                                                 ushort_t* __restrict__ xn_bf) {
  int row = blockIdx.x;
  const float4* xr = (const float4*)(x + (size_t)row * D_MODEL);
  float4 v = xr[threadIdx.x];
  float s  = v.x + v.y + v.z + v.w;
  float ss = v.x * v.x + v.y * v.y + v.z * v.z + v.w * v.w;
  #pragma unroll
  for (int o = 32; o; o >>= 1) { s += __shfl_down(s, o); ss += __shfl_down(ss, o); }
  __shared__ float sbuf[8], ssbuf[8];
  int wid = threadIdx.x >> 6, lane = threadIdx.x & 63;
  if (lane == 0) { sbuf[wid] = s; ssbuf[wid] = ss; }
  __syncthreads();
  if (threadIdx.x == 0) {
    float t = 0.f, t2 = 0.f;
    for (int i = 0; i < 4; i++) { t += sbuf[i]; t2 += ssbuf[i]; }
    float mu = t / D_MODEL;
    sbuf[4] = mu;
    ssbuf[4] = rsqrtf(t2 / D_MODEL - mu * mu + LN_EPS);
  }
  __syncthreads();
  float mu = sbuf[4], inv = ssbuf[4];
  float4 gv = ((const float4*)g)[threadIdx.x];
  float4 bv = ((const float4*)b)[threadIdx.x];
  ushort_t o4[4];
  o4[0] = f2bf((v.x - mu) * inv * gv.x + bv.x);
  o4[1] = f2bf((v.y - mu) * inv * gv.y + bv.y);
  o4[2] = f2bf((v.z - mu) * inv * gv.z + bv.z);
  o4[3] = f2bf((v.w - mu) * inv * gv.w + bv.w);
  *(ushort4*)&xn_bf[(size_t)row * D_MODEL + threadIdx.x * 4] =
      make_ushort4(o4[0], o4[1], o4[2], o4[3]);
}

// ---------------- bf16 MFMA GEMM, NT layout (A MxK row-major, B NxK row-major) ----------------
template <int BM, int BN, bool RESID>
__global__ __launch_bounds__(256) void gemm_bt(const ushort_t* __restrict__ A,
                                               const ushort_t* __restrict__ B,
                                               float* __restrict__ C,
                                               const float* __restrict__ R,
                                               int M, int N, int K) {
  constexpr int BK = 32;
  __shared__ __align__(16) ushort_t As[BM * BK];
  __shared__ __align__(16) ushort_t Bs[BN * BK];
  const int bm = blockIdx.y, bn = blockIdx.x;
  const int tid = threadIdx.x, wid = tid >> 6, lane = tid & 63;
  const int wm = wid >> 1, wn = wid & 1;          // 2x2 wave grid
  constexpr int WTM = BM / 2, WTN = BN / 2;
  constexpr int MREP = WTM / 16, NREP = WTN / 16;
  constexpr int A_ISS = BM / 64;                  // per-wave 1KB staging issues
  constexpr int B_ISS = BN / 64;

  f32x4 acc[MREP][NREP] = {};
  const int row0A = bm * BM, row0B = bn * BN;
  const int gr = lane >> 2, gc = lane & 3;        // staging row-in-block / 16B granule

  for (int k0 = 0; k0 < K; k0 += BK) {
    #pragma unroll
    for (int i = 0; i < A_ISS; i++) {
      int rb = i * 4 + wid;                       // 16-row block
      ushort_t* ldsp = As + rb * 512;             // wave-uniform base
      const ushort_t* g = A + (size_t)(row0A + rb * 16 + gr) * K + k0 + gc * 8;
      async16(ldsp, g);
    }
    #pragma unroll
    for (int i = 0; i < B_ISS; i++) {
      int rb = i * 4 + wid;
      ushort_t* ldsp = Bs + rb * 512;
      const ushort_t* g = B + (size_t)(row0B + rb * 16 + gr) * K + k0 + gc * 8;
      async16(ldsp, g);
    }
    __syncthreads();
    short8 af[MREP], bfr[NREP];
    #pragma unroll
    for (int i = 0; i < MREP; i++) {
      int r = wm * WTM + i * 16 + (lane & 15);
      af[i] = *(const short8*)&As[r * 32 + (lane >> 4) * 8];
    }
    #pragma unroll
    for (int j = 0; j < NREP; j++) {
      int r = wn * WTN + j * 16 + (lane & 15);
      bfr[j] = *(const short8*)&Bs[r * 32 + (lane >> 4) * 8];
    }
    #pragma unroll
    for (int i = 0; i < MREP; i++)
      #pragma unroll
      for (int j = 0; j < NREP; j++)
        acc[i][j] = __builtin_amdgcn_mfma_f32_16x16x32_bf16(af[i], bfr[j], acc[i][j], 0, 0, 0);
    __syncthreads();
  }

  #pragma unroll
  for (int i = 0; i < MREP; i++)
    #pragma unroll
    for (int j = 0; j < NREP; j++) {
      int r0 = row0A + wm * WTM + i * 16 + (lane >> 4) * 4;
      int c  = row0B + wn * WTN + j * 16 + (lane & 15);
      #pragma unroll
      for (int q = 0; q < 4; q++) {
        size_t idx = (size_t)(r0 + q) * N + c;
        float v = acc[i][j][q];
        if (RESID) v += R[idx];
        C[idx] = v;
      }
    }
}

// ---------------- depthwise causal conv + SiLU ----------------
__global__ __launch_bounds__(256) void conv_silu_kernel(const float* __restrict__ xz,
                                                        const float* __restrict__ cw,
                                                        const float* __restrict__ cb,
                                                        float* __restrict__ xs) {
  int idx = blockIdx.x * 256 + threadIdx.x;       // t*D_INNER + d
  int t = idx >> 11, d = idx & (D_INNER - 1);
  float acc = cb[d];
  #pragma unroll
  for (int k = 0; k < D_CONV; k++) {
    int tt = t - (D_CONV - 1) + k;
    if (tt >= 0) acc += xz[(size_t)tt * (2 * D_INNER) + d] * cw[d * D_CONV + k];
  }
  float sg = 1.f / (1.f + __expf(-acc));
  xs[idx] = acc * sg;
}

// ---------------- x_proj: xp[s,e] = dot(xs[s,:], w[e,:]), e in [0,33) ----------------
__global__ __launch_bounds__(256) void xproj_kernel(const float* __restrict__ xs,
                                                    const float* __restrict__ w,
                                                    float* __restrict__ xp) {
  int wid = threadIdx.x >> 6, lane = threadIdx.x & 63;
  int s = blockIdx.x * 4 + wid;
  const float* xr = xs + (size_t)s * D_INNER;
  float r[32];
  #pragma unroll
  for (int j = 0; j < 32; j++) r[j] = xr[lane + j * 64];
  for (int e = 0; e < 33; e++) {
    const float* we = w + (size_t)e * D_INNER;
    float a = 0.f;
    #pragma unroll
    for (int j = 0; j < 32; j++) a += r[j] * we[lane + j * 64];
    #pragma unroll
    for (int o = 32; o; o >>= 1) a += __shfl_down(a, o);
    if (lane == 0) xp[(size_t)s * 33 + e] = a;
  }
}

// ---------------- scan pass1: per-chunk product + partial state ----------------
__global__ __launch_bounds__(256) void scan_pass1(const float* __restrict__ xs,
                                                  const float* __restrict__ xp,
                                                  const float* __restrict__ dt_w,
                                                  const float* __restrict__ dt_b,
                                                  const float* __restrict__ A_log,
                                                  float* __restrict__ P,
                                                  float* __restrict__ Hp) {
  int c = blockIdx.x, g = blockIdx.y;
  int d = g * 256 + threadIdx.x;
  __shared__ float Bs[CLEN][16], drs[CLEN], As[16];
  for (int i = threadIdx.x; i < CLEN * 16; i += 256) {
    int t = i >> 4, n = i & 15;
    Bs[t][n] = xp[(size_t)(c * CLEN + t) * 33 + 1 + n];
  }
  if (threadIdx.x < CLEN) drs[threadIdx.x] = xp[(size_t)(c * CLEN + threadIdx.x) * 33];
  if (threadIdx.x < 16) As[threadIdx.x] = -__expf(A_log[threadIdx.x]);
  __syncthreads();
  float dw = dt_w[d], db = dt_b[d];
  float h[16], Pr[16];
  #pragma unroll
  for (int n = 0; n < 16; n++) { h[n] = 0.f; Pr[n] = 1.f; }
  for (int t = 0; t < CLEN; t++) {
    float pre = drs[t] * dw + db;
    float delta = (pre > 20.f) ? pre : log1pf(__expf(pre));
    float xv = xs[(size_t)(c * CLEN + t) * D_INNER + d];
    float w = delta * xv;
    #pragma unroll
    for (int n = 0; n < 16; n++) {
      float da = __expf(delta * As[n]);
      h[n] = da * h[n] + w * Bs[t][n];
      Pr[n] *= da;
    }
  }
  size_t base = ((size_t)c * D_INNER + d) * 16;
  #pragma unroll
  for (int n = 0; n < 16; n += 4) {
    *(float4*)&P[base + n]  = make_float4(Pr[n], Pr[n + 1], Pr[n + 2], Pr[n + 3]);
    *(float4*)&Hp[base + n] = make_float4(h[n], h[n + 1], h[n + 2], h[n + 3]);
  }
}

// ---------------- scan combine: prefix over chunks per (d,n) ----------------
__global__ __launch_bounds__(256) void scan_combine(const float* __restrict__ P,
                                                    const float* __restrict__ Hp,
                                                    float* __restrict__ Hin) {
  int idx = blockIdx.x * 256 + threadIdx.x;       // d*16 + n, total 32768
  float h = 0.f;
  const size_t stride = (size_t)D_INNER * 16;
  for (int c = 0; c < NCHUNK; c++) {
    Hin[(size_t)c * stride + idx] = h;
    h = P[(size_t)c * stride + idx] * h + Hp[(size_t)c * stride + idx];
  }
}

// ---------------- scan pass2: rescan + gating -> y_bf ----------------
__global__ __launch_bounds__(256) void scan_pass2(const float* __restrict__ xs,
                                                  const float* __restrict__ xp,
                                                  const float* __restrict__ xz,
                                                  const float* __restrict__ dt_w,
                                                  const float* __restrict__ dt_b,
                                                  const float* __restrict__ A_log,
                                                  const float* __restrict__ Dp,
                                                  const float* __restrict__ Hin,
                                                  ushort_t* __restrict__ y_bf) {
  int c = blockIdx.x, g = blockIdx.y;
  int d = g * 256 + threadIdx.x;
  __shared__ float Bs[CLEN][16], Cs[CLEN][16], drs[CLEN], As[16];
  for (int i = threadIdx.x; i < CLEN * 16; i += 256) {
    int t = i >> 4, n = i & 15;
    Bs[t][n] = xp[(size_t)(c * CLEN + t) * 33 + 1 + n];
    Cs[t][n] = xp[(size_t)(c * CLEN + t) * 33 + 17 + n];
  }
  if (threadIdx.x < CLEN) drs[threadIdx.x] = xp[(size_t)(c * CLEN + threadIdx.x) * 33];
  if (threadIdx.x < 16) As[threadIdx.x] = -__expf(A_log[threadIdx.x]);
  __syncthreads();
  float dw = dt_w[d], db = dt_b[d], Dd = Dp[d];
  float h[16];
  size_t hbase = ((size_t)c * D_INNER + d) * 16;
  #pragma unroll
  for (int n = 0; n < 16; n++) h[n] = Hin[hbase + n];
  for (int t = 0; t < CLEN; t++) {
    float pre = drs[t] * dw + db;
    float delta = (pre > 20.f) ? pre : log1pf(__expf(pre));
    size_t ti = (size_t)(c * CLEN + t);
    float xv = xs[ti * D_INNER + d];
    float w = delta * xv;
    float y = 0.f;
    #pragma unroll
    for (int n = 0; n < 16; n++) {
      float da = __expf(delta * As[n]);
      h[n] = da * h[n] + w * Bs[t][n];
      y += h[n] * Cs[t][n];
    }
    float z = xz[ti * (2 * D_INNER) + D_INNER + d];
    float sz = z / (1.f + __expf(-z));
    float out = (y + xv * Dd) * sz;
    y_bf[ti * D_INNER + d] = f2bf(out);
  }
}

// ---------------- launch ----------------
extern "C" void kernel_launch(void* const* d_in, const int* in_sizes, int n_in,
                              void* d_out, int out_size, void* d_ws, size_t ws_size,
                              hipStream_t stream) {
  const float* x      = (const float*)d_in[0];
  const float* ln_g   = (const float*)d_in[1];
  const float* ln_b   = (const float*)d_in[2];
  const float* in_w   = (const float*)d_in[3];
  const float* conv_w = (const float*)d_in[4];
  const float* conv_b = (const float*)d_in[5];
  const float* xproj_w= (const float*)d_in[6];
  const float* dt_w   = (const float*)d_in[7];
  const float* dt_b   = (const float*)d_in[8];
  const float* A_log  = (const float*)d_in[9];
  const float* Dp     = (const float*)d_in[10];
  const float* out_w  = (const float*)d_in[11];
  float* out = (float*)d_out;

  char* ws = (char*)d_ws;
  size_t off = 0;
  auto alloc = [&](size_t bytes) { char* p = ws + off; off += (bytes + 255) & ~(size_t)255; return p; };
  float*    xz      = (float*)   alloc((size_t)SEQ * 2 * D_INNER * 4);
  ushort_t* xn_bf   = (ushort_t*)alloc((size_t)SEQ * D_MODEL * 2);
  ushort_t* inw_bf  = (ushort_t*)alloc((size_t)2 * D_INNER * D_MODEL * 2);
  ushort_t* outw_bf = (ushort_t*)alloc((size_t)D_MODEL * D_INNER * 2);
  float*    xs      = (float*)   alloc((size_t)SEQ * D_INNER * 4);
  float*    xp      = (float*)   alloc((size_t)SEQ * 33 * 4);
  float*    Pb      = (float*)   alloc((size_t)NCHUNK * D_INNER * 16 * 4);
  float*    Hp      = (float*)   alloc((size_t)NCHUNK * D_INNER * 16 * 4);
  float*    Hin     = (float*)   alloc((size_t)NCHUNK * D_INNER * 16 * 4);
  ushort_t* y_bf    = (ushort_t*)alloc((size_t)SEQ * D_INNER * 2);
  (void)ws_size;

  // weights -> bf16  (6M elems)
  cvt_w_kernel<<<(2 * D_INNER * D_MODEL + D_MODEL * D_INNER + 255) / 256, 256, 0, stream>>>(
      in_w, out_w, inw_bf, outw_bf);
  // layernorm
  ln_kernel<<<SEQ, 256, 0, stream>>>(x, ln_g, ln_b, xn_bf);
  // in_proj: xz = xn @ in_w^T   (M=2048, N=4096, K=1024)
  gemm_bt<128, 128, false><<<dim3(2 * D_INNER / 128, SEQ / 128), 256, 0, stream>>>(
      xn_bf, inw_bf, xz, nullptr, SEQ, 2 * D_INNER, D_MODEL);
  // conv + silu
  conv_silu_kernel<<<SEQ * D_INNER / 256, 256, 0, stream>>>(xz, conv_w, conv_b, xs);
  // x_proj
  xproj_kernel<<<SEQ / 4, 256, 0, stream>>>(xs, xproj_w, xp);
  // scan
  scan_pass1<<<dim3(NCHUNK, D_INNER / 256), 256, 0, stream>>>(xs, xp, dt_w, dt_b, A_log, Pb, Hp);
  scan_combine<<<D_INNER * 16 / 256, 256, 0, stream>>>(Pb, Hp, Hin);
  scan_pass2<<<dim3(NCHUNK, D_INNER / 256), 256, 0, stream>>>(xs, xp, xz, dt_w, dt_b, A_log,
                                                              Dp, Hin, y_bf);
  // out_proj + residual  (M=2048, N=1024, K=2048)
  gemm_bt<64, 128, true><<<dim3(D_MODEL / 128, SEQ / 64), 256, 0, stream>>>(
      y_bf, outw_bf, out, x, SEQ, D_MODEL, D_INNER);
}

// Round 2
// 189.671 us; speedup vs baseline: 1.1031x; 1.1031x over previous
//
#include <hip/hip_runtime.h>
#include <cstdint>
#include <cstddef>

#define D_MODEL 1024
#define D_STATE 16
#define D_CONV  4
#define D_INNER 2048
#define SEQ     2048
#define NCHUNK  128
#define CLEN    16
#define LN_EPS  1e-5f

typedef unsigned short ushort_t;
typedef __attribute__((ext_vector_type(8))) short short8;
typedef __attribute__((ext_vector_type(4))) float f32x4;

__device__ __forceinline__ ushort_t f2bf(float x) {
  union { float f; uint32_t u; } v; v.f = x;
  uint32_t r = (v.u + 0x7fffu + ((v.u >> 16) & 1u)) >> 16;
  return (ushort_t)r;
}

__device__ __forceinline__ void async16(void* lds, const void* g) {
  __builtin_amdgcn_global_load_lds(
      (const __attribute__((address_space(1))) unsigned int*)g,
      (__attribute__((address_space(3))) unsigned int*)lds, 16, 0, 0);
}

__device__ __forceinline__ float softplus_f(float x) {
  // accurate enough for |err| << bf16 ulp; exact-ish for large |x|
  if (x > 20.f) return x;
  if (x < -20.f) return __expf(x);
  return __logf(1.f + __expf(x));
}

// ---------------- weight conversion (f32 -> bf16) ----------------
__global__ void cvt_w_kernel(const float* __restrict__ inw,
                             const float* __restrict__ outw,
                             ushort_t* __restrict__ inw_bf,
                             ushort_t* __restrict__ outw_bf) {
  int idx = blockIdx.x * 256 + threadIdx.x;
  const int n1 = 2 * D_INNER * D_MODEL;
  const int n2 = D_MODEL * D_INNER;
  if (idx < n1) {
    inw_bf[idx] = f2bf(inw[idx]);
  } else {
    int j = idx - n1;
    if (j < n2) outw_bf[j] = f2bf(outw[j]);
  }
}

// ---------------- LayerNorm -> bf16 ----------------
__global__ __launch_bounds__(256) void ln_kernel(const float* __restrict__ x,
                                                 const float* __restrict__ g,
                                                 const float* __restrict__ b,
                                                 ushort_t* __restrict__ xn_bf) {
  int row = blockIdx.x;
  const float4* xr = (const float4*)(x + (size_t)row * D_MODEL);
  float4 v = xr[threadIdx.x];
  float s  = v.x + v.y + v.z + v.w;
  float ss = v.x * v.x + v.y * v.y + v.z * v.z + v.w * v.w;
  #pragma unroll
  for (int o = 32; o; o >>= 1) { s += __shfl_down(s, o); ss += __shfl_down(ss, o); }
  __shared__ float sbuf[8], ssbuf[8];
  int wid = threadIdx.x >> 6, lane = threadIdx.x & 63;
  if (lane == 0) { sbuf[wid] = s; ssbuf[wid] = ss; }
  __syncthreads();
  if (threadIdx.x == 0) {
    float t = 0.f, t2 = 0.f;
    for (int i = 0; i < 4; i++) { t += sbuf[i]; t2 += ssbuf[i]; }
    float mu = t / D_MODEL;
    sbuf[4] = mu;
    ssbuf[4] = rsqrtf(t2 / D_MODEL - mu * mu + LN_EPS);
  }
  __syncthreads();
  float mu = sbuf[4], inv = ssbuf[4];
  float4 gv = ((const float4*)g)[threadIdx.x];
  float4 bv = ((const float4*)b)[threadIdx.x];
  ushort_t o4[4];
  o4[0] = f2bf((v.x - mu) * inv * gv.x + bv.x);
  o4[1] = f2bf((v.y - mu) * inv * gv.y + bv.y);
  o4[2] = f2bf((v.z - mu) * inv * gv.z + bv.z);
  o4[3] = f2bf((v.w - mu) * inv * gv.w + bv.w);
  *(ushort4*)&xn_bf[(size_t)row * D_MODEL + threadIdx.x * 4] =
      make_ushort4(o4[0], o4[1], o4[2], o4[3]);
}

// ---------------- bf16 MFMA GEMM, NT layout, XCD-swizzled ----------------
template <int BM, int BN, bool RESID>
__global__ __launch_bounds__(256) void gemm_bt(const ushort_t* __restrict__ A,
                                               const ushort_t* __restrict__ B,
                                               float* __restrict__ C,
                                               const float* __restrict__ R,
                                               int M, int N, int K) {
  constexpr int BK = 32;
  __shared__ __align__(16) ushort_t As[BM * BK];
  __shared__ __align__(16) ushort_t Bs[BN * BK];
  // bijective XCD swizzle (gridDim.x*gridDim.y % 8 == 0 for our shapes)
  int nwg = gridDim.x * gridDim.y;
  int bid = blockIdx.y * gridDim.x + blockIdx.x;
  int swz = (bid & 7) * (nwg >> 3) + (bid >> 3);
  const int bn = swz % gridDim.x, bm = swz / gridDim.x;
  const int tid = threadIdx.x, wid = tid >> 6, lane = tid & 63;
  const int wm = wid >> 1, wn = wid & 1;
  constexpr int WTM = BM / 2, WTN = BN / 2;
  constexpr int MREP = WTM / 16, NREP = WTN / 16;
  constexpr int A_ISS = BM / 64;
  constexpr int B_ISS = BN / 64;

  f32x4 acc[MREP][NREP] = {};
  const int row0A = bm * BM, row0B = bn * BN;
  const int gr = lane >> 2, gc = lane & 3;

  for (int k0 = 0; k0 < K; k0 += BK) {
    #pragma unroll
    for (int i = 0; i < A_ISS; i++) {
      int rb = i * 4 + wid;
      ushort_t* ldsp = As + rb * 512;
      const ushort_t* g = A + (size_t)(row0A + rb * 16 + gr) * K + k0 + gc * 8;
      async16(ldsp, g);
    }
    #pragma unroll
    for (int i = 0; i < B_ISS; i++) {
      int rb = i * 4 + wid;
      ushort_t* ldsp = Bs + rb * 512;
      const ushort_t* g = B + (size_t)(row0B + rb * 16 + gr) * K + k0 + gc * 8;
      async16(ldsp, g);
    }
    __syncthreads();
    short8 af[MREP], bfr[NREP];
    #pragma unroll
    for (int i = 0; i < MREP; i++) {
      int r = wm * WTM + i * 16 + (lane & 15);
      af[i] = *(const short8*)&As[r * 32 + (lane >> 4) * 8];
    }
    #pragma unroll
    for (int j = 0; j < NREP; j++) {
      int r = wn * WTN + j * 16 + (lane & 15);
      bfr[j] = *(const short8*)&Bs[r * 32 + (lane >> 4) * 8];
    }
    #pragma unroll
    for (int i = 0; i < MREP; i++)
      #pragma unroll
      for (int j = 0; j < NREP; j++)
        acc[i][j] = __builtin_amdgcn_mfma_f32_16x16x32_bf16(af[i], bfr[j], acc[i][j], 0, 0, 0);
    __syncthreads();
  }

  #pragma unroll
  for (int i = 0; i < MREP; i++)
    #pragma unroll
    for (int j = 0; j < NREP; j++) {
      int r0 = row0A + wm * WTM + i * 16 + (lane >> 4) * 4;
      int c  = row0B + wn * WTN + j * 16 + (lane & 15);
      #pragma unroll
      for (int q = 0; q < 4; q++) {
        size_t idx = (size_t)(r0 + q) * N + c;
        float v = acc[i][j][q];
        if (RESID) v += R[idx];
        C[idx] = v;
      }
    }
}

// ---------------- depthwise causal conv + SiLU ----------------
__global__ __launch_bounds__(256) void conv_silu_kernel(const float* __restrict__ xz,
                                                        const float* __restrict__ cw,
                                                        const float* __restrict__ cb,
                                                        float* __restrict__ xs) {
  int idx = blockIdx.x * 256 + threadIdx.x;
  int t = idx >> 11, d = idx & (D_INNER - 1);
  float acc = cb[d];
  #pragma unroll
  for (int k = 0; k < D_CONV; k++) {
    int tt = t - (D_CONV - 1) + k;
    if (tt >= 0) acc += xz[(size_t)tt * (2 * D_INNER) + d] * cw[d * D_CONV + k];
  }
  float sg = 1.f / (1.f + __expf(-acc));
  xs[idx] = acc * sg;
}

// ---------------- x_proj ----------------
__global__ __launch_bounds__(256) void xproj_kernel(const float* __restrict__ xs,
                                                    const float* __restrict__ w,
                                                    float* __restrict__ xp) {
  int wid = threadIdx.x >> 6, lane = threadIdx.x & 63;
  int s = blockIdx.x * 4 + wid;
  const float* xr = xs + (size_t)s * D_INNER;
  float r[32];
  #pragma unroll
  for (int j = 0; j < 32; j++) r[j] = xr[lane + j * 64];
  for (int e = 0; e < 33; e++) {
    const float* we = w + (size_t)e * D_INNER;
    float a = 0.f;
    #pragma unroll
    for (int j = 0; j < 32; j++) a += r[j] * we[lane + j * 64];
    #pragma unroll
    for (int o = 32; o; o >>= 1) a += __shfl_down(a, o);
    if (lane == 0) xp[(size_t)s * 33 + e] = a;
  }
}

// ---------------- scan pass1: per-chunk partial state + sum(delta) ----------------
__global__ __launch_bounds__(256) void scan_pass1(const float* __restrict__ xs,
                                                  const float* __restrict__ xp,
                                                  const float* __restrict__ dt_w,
                                                  const float* __restrict__ dt_b,
                                                  const float* __restrict__ A_log,
                                                  float* __restrict__ Hp,
                                                  float* __restrict__ Sd) {
  int c = blockIdx.x, g = blockIdx.y;
  int d = g * 256 + threadIdx.x;
  __shared__ float Bs[CLEN][16], drs[CLEN], As[16];
  {
    int t = threadIdx.x >> 4, n = threadIdx.x & 15;
    Bs[t][n] = xp[(size_t)(c * CLEN + t) * 33 + 1 + n];
    if (threadIdx.x < CLEN) drs[threadIdx.x] = xp[(size_t)(c * CLEN + threadIdx.x) * 33];
    else if (threadIdx.x < CLEN + 16) {
      int n2 = threadIdx.x - CLEN;
      As[n2] = -__expf(A_log[n2]);
    }
  }
  __syncthreads();
  bool fastA = true;
  #pragma unroll
  for (int n = 0; n < 16; n++) fastA = fastA && (fabsf(As[n] + (float)(n + 1)) < 1e-4f * (n + 1));
  float dw = dt_w[d], db = dt_b[d];
  float h[16];
  float S = 0.f;
  #pragma unroll
  for (int n = 0; n < 16; n++) h[n] = 0.f;
  for (int t = 0; t < CLEN; t++) {
    float delta = softplus_f(drs[t] * dw + db);
    S += delta;
    float xv = xs[(size_t)(c * CLEN + t) * D_INNER + d];
    float w = delta * xv;
    float bb[16];
    *(float4*)&bb[0]  = *(const float4*)&Bs[t][0];
    *(float4*)&bb[4]  = *(const float4*)&Bs[t][4];
    *(float4*)&bb[8]  = *(const float4*)&Bs[t][8];
    *(float4*)&bb[12] = *(const float4*)&Bs[t][12];
    if (fastA) {
      float g1 = __expf(-delta);
      float da = 1.f;
      #pragma unroll
      for (int n = 0; n < 16; n++) {
        da *= g1;
        h[n] = da * h[n] + w * bb[n];
      }
    } else {
      #pragma unroll
      for (int n = 0; n < 16; n++) {
        float da = __expf(delta * As[n]);
        h[n] = da * h[n] + w * bb[n];
      }
    }
  }
  size_t base = ((size_t)c * D_INNER + d) * 16;
  #pragma unroll
  for (int n = 0; n < 16; n += 4)
    *(float4*)&Hp[base + n] = make_float4(h[n], h[n + 1], h[n + 2], h[n + 3]);
  Sd[(size_t)c * D_INNER + d] = S;
}

// ---------------- scan combine: exclusive prefix over chunks per (d,n) ----------------
// chunk product over states is exactly exp(A_n * sum(delta)) — generic identity.
__global__ __launch_bounds__(256) void scan_combine(const float* __restrict__ Hp,
                                                    const float* __restrict__ Sd,
                                                    const float* __restrict__ A_log,
                                                    float* __restrict__ Hin) {
  int idx = blockIdx.x * 256 + threadIdx.x;     // d*16 + n
  int d = idx >> 4, n = idx & 15;
  float An = -__expf(A_log[n]);
  float h = 0.f;
  const size_t stride = (size_t)D_INNER * 16;
  #pragma unroll 4
  for (int c = 0; c < NCHUNK; c++) {
    float S  = Sd[(size_t)c * D_INNER + d];
    float hp = Hp[(size_t)c * stride + idx];
    Hin[(size_t)c * stride + idx] = h;
    h = __expf(An * S) * h + hp;
  }
}

// ---------------- scan pass2: rescan + gating -> y_bf ----------------
__global__ __launch_bounds__(256) void scan_pass2(const float* __restrict__ xs,
                                                  const float* __restrict__ xp,
                                                  const float* __restrict__ xz,
                                                  const float* __restrict__ dt_w,
                                                  const float* __restrict__ dt_b,
                                                  const float* __restrict__ A_log,
                                                  const float* __restrict__ Dp,
                                                  const float* __restrict__ Hin,
                                                  ushort_t* __restrict__ y_bf) {
  int c = blockIdx.x, g = blockIdx.y;
  int d = g * 256 + threadIdx.x;
  __shared__ float Bs[CLEN][16], Cs[CLEN][16], drs[CLEN], As[16];
  {
    int t = threadIdx.x >> 4, n = threadIdx.x & 15;
    Bs[t][n] = xp[(size_t)(c * CLEN + t) * 33 + 1 + n];
    Cs[t][n] = xp[(size_t)(c * CLEN + t) * 33 + 17 + n];
    if (threadIdx.x < CLEN) drs[threadIdx.x] = xp[(size_t)(c * CLEN + threadIdx.x) * 33];
    else if (threadIdx.x < CLEN + 16) {
      int n2 = threadIdx.x - CLEN;
      As[n2] = -__expf(A_log[n2]);
    }
  }
  __syncthreads();
  bool fastA = true;
  #pragma unroll
  for (int n = 0; n < 16; n++) fastA = fastA && (fabsf(As[n] + (float)(n + 1)) < 1e-4f * (n + 1));
  float dw = dt_w[d], db = dt_b[d], Dd = Dp[d];
  float h[16];
  size_t hbase = ((size_t)c * D_INNER + d) * 16;
  #pragma unroll
  for (int n = 0; n < 16; n += 4)
    *(float4*)&h[n] = *(const float4*)&Hin[hbase + n];
  for (int t = 0; t < CLEN; t++) {
    float delta = softplus_f(drs[t] * dw + db);
    size_t ti = (size_t)(c * CLEN + t);
    float xv = xs[ti * D_INNER + d];
    float w = delta * xv;
    float bb[16], cc[16];
    *(float4*)&bb[0]  = *(const float4*)&Bs[t][0];
    *(float4*)&bb[4]  = *(const float4*)&Bs[t][4];
    *(float4*)&bb[8]  = *(const float4*)&Bs[t][8];
    *(float4*)&bb[12] = *(const float4*)&Bs[t][12];
    *(float4*)&cc[0]  = *(const float4*)&Cs[t][0];
    *(float4*)&cc[4]  = *(const float4*)&Cs[t][4];
    *(float4*)&cc[8]  = *(const float4*)&Cs[t][8];
    *(float4*)&cc[12] = *(const float4*)&Cs[t][12];
    float y = 0.f;
    if (fastA) {
      float g1 = __expf(-delta);
      float da = 1.f;
      #pragma unroll
      for (int n = 0; n < 16; n++) {
        da *= g1;
        h[n] = da * h[n] + w * bb[n];
        y += h[n] * cc[n];
      }
    } else {
      #pragma unroll
      for (int n = 0; n < 16; n++) {
        float da = __expf(delta * As[n]);
        h[n] = da * h[n] + w * bb[n];
        y += h[n] * cc[n];
      }
    }
    float z = xz[ti * (2 * D_INNER) + D_INNER + d];
    float sz = z / (1.f + __expf(-z));
    float out = (y + xv * Dd) * sz;
    y_bf[ti * D_INNER + d] = f2bf(out);
  }
}

// ---------------- launch ----------------
extern "C" void kernel_launch(void* const* d_in, const int* in_sizes, int n_in,
                              void* d_out, int out_size, void* d_ws, size_t ws_size,
                              hipStream_t stream) {
  const float* x      = (const float*)d_in[0];
  const float* ln_g   = (const float*)d_in[1];
  const float* ln_b   = (const float*)d_in[2];
  const float* in_w   = (const float*)d_in[3];
  const float* conv_w = (const float*)d_in[4];
  const float* conv_b = (const float*)d_in[5];
  const float* xproj_w= (const float*)d_in[6];
  const float* dt_w   = (const float*)d_in[7];
  const float* dt_b   = (const float*)d_in[8];
  const float* A_log  = (const float*)d_in[9];
  const float* Dp     = (const float*)d_in[10];
  const float* out_w  = (const float*)d_in[11];
  float* out = (float*)d_out;

  char* ws = (char*)d_ws;
  size_t off = 0;
  auto alloc = [&](size_t bytes) { char* p = ws + off; off += (bytes + 255) & ~(size_t)255; return p; };
  float*    xz      = (float*)   alloc((size_t)SEQ * 2 * D_INNER * 4);
  ushort_t* xn_bf   = (ushort_t*)alloc((size_t)SEQ * D_MODEL * 2);
  ushort_t* inw_bf  = (ushort_t*)alloc((size_t)2 * D_INNER * D_MODEL * 2);
  ushort_t* outw_bf = (ushort_t*)alloc((size_t)D_MODEL * D_INNER * 2);
  float*    xs      = (float*)   alloc((size_t)SEQ * D_INNER * 4);
  float*    xp      = (float*)   alloc((size_t)SEQ * 33 * 4);
  float*    Hp      = (float*)   alloc((size_t)NCHUNK * D_INNER * 16 * 4);
  float*    Hin     = (float*)   alloc((size_t)NCHUNK * D_INNER * 16 * 4);
  float*    Sd      = (float*)   alloc((size_t)NCHUNK * D_INNER * 4);
  ushort_t* y_bf    = (ushort_t*)alloc((size_t)SEQ * D_INNER * 2);
  (void)ws_size;

  cvt_w_kernel<<<(2 * D_INNER * D_MODEL + D_MODEL * D_INNER + 255) / 256, 256, 0, stream>>>(
      in_w, out_w, inw_bf, outw_bf);
  ln_kernel<<<SEQ, 256, 0, stream>>>(x, ln_g, ln_b, xn_bf);
  gemm_bt<128, 128, false><<<dim3(2 * D_INNER / 128, SEQ / 128), 256, 0, stream>>>(
      xn_bf, inw_bf, xz, nullptr, SEQ, 2 * D_INNER, D_MODEL);
  conv_silu_kernel<<<SEQ * D_INNER / 256, 256, 0, stream>>>(xz, conv_w, conv_b, xs);
  xproj_kernel<<<SEQ / 4, 256, 0, stream>>>(xs, xproj_w, xp);
  scan_pass1<<<dim3(NCHUNK, D_INNER / 256), 256, 0, stream>>>(xs, xp, dt_w, dt_b, A_log, Hp, Sd);
  scan_combine<<<D_INNER * 16 / 256, 256, 0, stream>>>(Hp, Sd, A_log, Hin);
  scan_pass2<<<dim3(NCHUNK, D_INNER / 256), 256, 0, stream>>>(xs, xp, xz, dt_w, dt_b, A_log,
                                                              Dp, Hin, y_bf);
  gemm_bt<64, 128, true><<<dim3(D_MODEL / 128, SEQ / 64), 256, 0, stream>>>(
      y_bf, outw_bf, out, x, SEQ, D_MODEL, D_INNER);
}

// Round 3
// 188.447 us; speedup vs baseline: 1.1103x; 1.0065x over previous
//
#include <hip/hip_runtime.h>
#include <cstdint>
#include <cstddef>

#define D_MODEL 1024
#define D_STATE 16
#define D_CONV  4
#define D_INNER 2048
#define SEQ     2048
#define NCHUNK  128
#define CLEN    16
#define LN_EPS  1e-5f

typedef unsigned short ushort_t;
typedef __attribute__((ext_vector_type(8))) short short8;
typedef __attribute__((ext_vector_type(4))) float f32x4;

__device__ __forceinline__ ushort_t f2bf(float x) {
  union { float f; uint32_t u; } v; v.f = x;
  uint32_t r = (v.u + 0x7fffu + ((v.u >> 16) & 1u)) >> 16;
  return (ushort_t)r;
}
__device__ __forceinline__ float bf2f(ushort_t u) {
  union { uint32_t x; float f; } v; v.x = ((uint32_t)u) << 16; return v.f;
}

__device__ __forceinline__ void async16(void* lds, const void* g) {
  __builtin_amdgcn_global_load_lds(
      (const __attribute__((address_space(1))) unsigned int*)g,
      (__attribute__((address_space(3))) unsigned int*)lds, 16, 0, 0);
}

__device__ __forceinline__ float softplus_f(float x) {
  if (x > 20.f) return x;
  if (x < -20.f) return __expf(x);
  return __logf(1.f + __expf(x));
}

// ---------------- weight conversion (f32 -> bf16) ----------------
__global__ void cvt_w_kernel(const float* __restrict__ inw,
                             const float* __restrict__ outw,
                             ushort_t* __restrict__ inw_bf,
                             ushort_t* __restrict__ outw_bf) {
  int idx = blockIdx.x * 256 + threadIdx.x;
  const int n1 = 2 * D_INNER * D_MODEL;
  const int n2 = D_MODEL * D_INNER;
  if (idx < n1) {
    inw_bf[idx] = f2bf(inw[idx]);
  } else {
    int j = idx - n1;
    if (j < n2) outw_bf[j] = f2bf(outw[j]);
  }
}

// ---------------- LayerNorm -> bf16 ----------------
__global__ __launch_bounds__(256) void ln_kernel(const float* __restrict__ x,
                                                 const float* __restrict__ g,
                                                 const float* __restrict__ b,
                                                 ushort_t* __restrict__ xn_bf) {
  int row = blockIdx.x;
  const float4* xr = (const float4*)(x + (size_t)row * D_MODEL);
  float4 v = xr[threadIdx.x];
  float s  = v.x + v.y + v.z + v.w;
  float ss = v.x * v.x + v.y * v.y + v.z * v.z + v.w * v.w;
  #pragma unroll
  for (int o = 32; o; o >>= 1) { s += __shfl_down(s, o); ss += __shfl_down(ss, o); }
  __shared__ float sbuf[8], ssbuf[8];
  int wid = threadIdx.x >> 6, lane = threadIdx.x & 63;
  if (lane == 0) { sbuf[wid] = s; ssbuf[wid] = ss; }
  __syncthreads();
  if (threadIdx.x == 0) {
    float t = 0.f, t2 = 0.f;
    for (int i = 0; i < 4; i++) { t += sbuf[i]; t2 += ssbuf[i]; }
    float mu = t / D_MODEL;
    sbuf[4] = mu;
    ssbuf[4] = rsqrtf(t2 / D_MODEL - mu * mu + LN_EPS);
  }
  __syncthreads();
  float mu = sbuf[4], inv = ssbuf[4];
  float4 gv = ((const float4*)g)[threadIdx.x];
  float4 bv = ((const float4*)b)[threadIdx.x];
  ushort_t o4[4];
  o4[0] = f2bf((v.x - mu) * inv * gv.x + bv.x);
  o4[1] = f2bf((v.y - mu) * inv * gv.y + bv.y);
  o4[2] = f2bf((v.z - mu) * inv * gv.z + bv.z);
  o4[3] = f2bf((v.w - mu) * inv * gv.w + bv.w);
  *(ushort4*)&xn_bf[(size_t)row * D_MODEL + threadIdx.x * 4] =
      make_ushort4(o4[0], o4[1], o4[2], o4[3]);
}

// ---------------- pipelined MFMA GEMM (in_proj), NT layout, bf16 out ----------------
// 256x128 block tile, BK=32, triple-buffered LDS, counted vmcnt, 4 waves (2x2),
// wave-tile 128x64, XOR LDS swizzle (byte ^= (row&3)<<4) pre-applied on global src.
template <int KDIM>
__global__ __launch_bounds__(256, 2) void gemm_pipe(const ushort_t* __restrict__ A,
                                                    const ushort_t* __restrict__ B,
                                                    ushort_t* __restrict__ C,
                                                    int M, int N) {
  constexpr int NT = KDIM / 32;
  constexpr int K2 = KDIM * 2;          // row stride in bytes
  __shared__ __align__(16) ushort_t As[3][256 * 32];
  __shared__ __align__(16) ushort_t Bs[3][128 * 32];
  const int nwgx = N >> 7;
  const int nwg  = nwgx * (M >> 8);
  int bid = blockIdx.y * gridDim.x + blockIdx.x;
  int swz = (bid & 7) * (nwg >> 3) + (bid >> 3);
  const int bn = swz % nwgx, bm = swz / nwgx;
  const int tid = threadIdx.x, wid = tid >> 6, lane = tid & 63;
  const int wm = wid >> 1, wn = wid & 1;
  const int row0A = bm << 8, row0B = bn << 7;

  // per-thread staging sources (pre-swizzled global addresses), k0 = 0
  const char* gA[4];
  const char* gB[2];
  #pragma unroll
  for (int i = 0; i < 4; i++) {
    int o = i * 4096 + tid * 16;
    int r = o >> 6, src = (o & 63) ^ ((r & 3) << 4);
    gA[i] = (const char*)A + (size_t)(row0A + r) * K2 + src;
  }
  #pragma unroll
  for (int i = 0; i < 2; i++) {
    int o = i * 4096 + tid * 16;
    int r = o >> 6, src = (o & 63) ^ ((r & 3) << 4);
    gB[i] = (const char*)B + (size_t)(row0B + r) * K2 + src;
  }
  const int ldsA = wid * 1024;          // wave-uniform LDS byte offset

  auto STAGE = [&](int b, int kt) {
    int kb = kt * 64;                   // K advance in bytes
    #pragma unroll
    for (int i = 0; i < 4; i++)
      async16((char*)&As[b][0] + i * 4096 + ldsA, gA[i] + kb);
    #pragma unroll
    for (int i = 0; i < 2; i++)
      async16((char*)&Bs[b][0] + i * 4096 + ldsA, gB[i] + kb);
  };

  STAGE(0, 0);
  STAGE(1, 1);

  // fragment LDS byte offsets (constant across tiles)
  int offA[8], offB[4];
  #pragma unroll
  for (int m = 0; m < 8; m++) {
    int row = wm * 128 + m * 16 + (lane & 15);
    offA[m] = row * 64 + ((((lane >> 4)) ^ (row & 3)) << 4);
  }
  #pragma unroll
  for (int n = 0; n < 4; n++) {
    int row = wn * 64 + n * 16 + (lane & 15);
    offB[n] = row * 64 + ((((lane >> 4)) ^ (row & 3)) << 4);
  }

  f32x4 acc[8][4] = {};
  int cur = 0;
  for (int kt = 0; kt < NT; kt++) {
    __builtin_amdgcn_s_barrier();
    if (kt < NT - 1) { asm volatile("s_waitcnt vmcnt(6)" ::: "memory"); }
    else             { asm volatile("s_waitcnt vmcnt(0)" ::: "memory"); }
    __builtin_amdgcn_sched_barrier(0);
    const char* Ab = (const char*)&As[cur][0];
    const char* Bb = (const char*)&Bs[cur][0];
    short8 af[8], bf[4];
    #pragma unroll
    for (int m = 0; m < 8; m++) af[m] = *(const short8*)(Ab + offA[m]);
    #pragma unroll
    for (int n = 0; n < 4; n++) bf[n] = *(const short8*)(Bb + offB[n]);
    if (kt + 2 < NT) {
      int b2 = cur + 2; if (b2 >= 3) b2 -= 3;
      STAGE(b2, kt + 2);
    }
    __builtin_amdgcn_s_setprio(1);
    #pragma unroll
    for (int m = 0; m < 8; m++)
      #pragma unroll
      for (int n = 0; n < 4; n++)
        acc[m][n] = __builtin_amdgcn_mfma_f32_16x16x32_bf16(af[m], bf[n], acc[m][n], 0, 0, 0);
    __builtin_amdgcn_s_setprio(0);
    cur++; if (cur == 3) cur = 0;
  }

  #pragma unroll
  for (int m = 0; m < 8; m++)
    #pragma unroll
    for (int n = 0; n < 4; n++) {
      int r0 = row0A + wm * 128 + m * 16 + ((lane >> 4) << 2);
      int c  = row0B + wn * 64 + n * 16 + (lane & 15);
      #pragma unroll
      for (int q = 0; q < 4; q++)
        C[(size_t)(r0 + q) * N + c] = f2bf(acc[m][n][q]);
    }
}

// ---------------- 2-phase MFMA GEMM (out_proj), f32 out + residual ----------------
template <int BM, int BN>
__global__ __launch_bounds__(256) void gemm_bt(const ushort_t* __restrict__ A,
                                               const ushort_t* __restrict__ B,
                                               float* __restrict__ C,
                                               const float* __restrict__ R,
                                               int M, int N, int K) {
  constexpr int BK = 32;
  __shared__ __align__(16) ushort_t As[BM * BK];
  __shared__ __align__(16) ushort_t Bs[BN * BK];
  int nwg = gridDim.x * gridDim.y;
  int bid = blockIdx.y * gridDim.x + blockIdx.x;
  int swz = (bid & 7) * (nwg >> 3) + (bid >> 3);
  const int bn = swz % gridDim.x, bm = swz / gridDim.x;
  const int tid = threadIdx.x, wid = tid >> 6, lane = tid & 63;
  const int wm = wid >> 1, wn = wid & 1;
  constexpr int WTM = BM / 2, WTN = BN / 2;
  constexpr int MREP = WTM / 16, NREP = WTN / 16;
  constexpr int A_ISS = BM / 64;
  constexpr int B_ISS = BN / 64;

  f32x4 acc[MREP][NREP] = {};
  const int row0A = bm * BM, row0B = bn * BN;
  const int gr = lane >> 2, gc = lane & 3;

  for (int k0 = 0; k0 < K; k0 += BK) {
    #pragma unroll
    for (int i = 0; i < A_ISS; i++) {
      int rb = i * 4 + wid;
      ushort_t* ldsp = As + rb * 512;
      const ushort_t* g = A + (size_t)(row0A + rb * 16 + gr) * K + k0 + gc * 8;
      async16(ldsp, g);
    }
    #pragma unroll
    for (int i = 0; i < B_ISS; i++) {
      int rb = i * 4 + wid;
      ushort_t* ldsp = Bs + rb * 512;
      const ushort_t* g = B + (size_t)(row0B + rb * 16 + gr) * K + k0 + gc * 8;
      async16(ldsp, g);
    }
    __syncthreads();
    short8 af[MREP], bfr[NREP];
    #pragma unroll
    for (int i = 0; i < MREP; i++) {
      int r = wm * WTM + i * 16 + (lane & 15);
      af[i] = *(const short8*)&As[r * 32 + (lane >> 4) * 8];
    }
    #pragma unroll
    for (int j = 0; j < NREP; j++) {
      int r = wn * WTN + j * 16 + (lane & 15);
      bfr[j] = *(const short8*)&Bs[r * 32 + (lane >> 4) * 8];
    }
    #pragma unroll
    for (int i = 0; i < MREP; i++)
      #pragma unroll
      for (int j = 0; j < NREP; j++)
        acc[i][j] = __builtin_amdgcn_mfma_f32_16x16x32_bf16(af[i], bfr[j], acc[i][j], 0, 0, 0);
    __syncthreads();
  }

  #pragma unroll
  for (int i = 0; i < MREP; i++)
    #pragma unroll
    for (int j = 0; j < NREP; j++) {
      int r0 = row0A + wm * WTM + i * 16 + (lane >> 4) * 4;
      int c  = row0B + wn * WTN + j * 16 + (lane & 15);
      #pragma unroll
      for (int q = 0; q < 4; q++) {
        size_t idx = (size_t)(r0 + q) * N + c;
        C[idx] = acc[i][j][q] + R[idx];
      }
    }
}

// ---------------- fused depthwise conv + SiLU + x_proj ----------------
__global__ __launch_bounds__(256) void convxp_kernel(const ushort_t* __restrict__ xz_bf,
                                                     const float* __restrict__ cw,
                                                     const float* __restrict__ cb,
                                                     const float* __restrict__ w,
                                                     ushort_t* __restrict__ xs_bf,
                                                     float* __restrict__ xp) {
  int wid = threadIdx.x >> 6, lane = threadIdx.x & 63;
  int s = blockIdx.x * 4 + wid;
  const size_t rs = 2 * D_INNER;
  float r[32];
  #pragma unroll
  for (int j = 0; j < 32; j++) {
    int d = lane + j * 64;
    float4 cwv = ((const float4*)cw)[d];
    float acc = cb[d];
    const float* cwp = (const float*)&cwv;
    #pragma unroll
    for (int k = 0; k < 4; k++) {
      int tt = s - 3 + k;
      if (tt >= 0) acc += bf2f(xz_bf[(size_t)tt * rs + d]) * cwp[k];
    }
    float sg = 1.f / (1.f + __expf(-acc));
    r[j] = acc * sg;
    xs_bf[(size_t)s * D_INNER + d] = f2bf(r[j]);
  }
  for (int e = 0; e < 33; e++) {
    const float* we = w + (size_t)e * D_INNER;
    float a = 0.f;
    #pragma unroll
    for (int j = 0; j < 32; j++) a += r[j] * we[lane + j * 64];
    #pragma unroll
    for (int o = 32; o; o >>= 1) a += __shfl_down(a, o);
    if (lane == 0) xp[(size_t)s * 33 + e] = a;
  }
}

// da[n] = g1^(n+1), log-depth (no 16-long dependent chain)
__device__ __forceinline__ void dapow(float g1, float* da) {
  float g2 = g1 * g1, g4 = g2 * g2, g8 = g4 * g4;
  #pragma unroll
  for (int n = 0; n < 16; n++) {
    int e = n + 1;
    float v = (e & 1) ? g1 : 1.f;
    if (e & 2) v *= g2;
    if (e & 4) v *= g4;
    if (e & 8) v *= g8;
    da[n] = v;
  }
}

// ---------------- scan pass1 ----------------
__global__ __launch_bounds__(256) void scan_pass1(const ushort_t* __restrict__ xs_bf,
                                                  const float* __restrict__ xp,
                                                  const float* __restrict__ dt_w,
                                                  const float* __restrict__ dt_b,
                                                  const float* __restrict__ A_log,
                                                  float* __restrict__ Hp,
                                                  float* __restrict__ Sd) {
  int c = blockIdx.x, g = blockIdx.y;
  int d = g * 256 + threadIdx.x;
  __shared__ float Bsh[CLEN][16], drs[CLEN], Ash[16];
  {
    int t = threadIdx.x >> 4, n = threadIdx.x & 15;
    Bsh[t][n] = xp[(size_t)(c * CLEN + t) * 33 + 1 + n];
    if (threadIdx.x < CLEN) drs[threadIdx.x] = xp[(size_t)(c * CLEN + threadIdx.x) * 33];
    else if (threadIdx.x < CLEN + 16) {
      int n2 = threadIdx.x - CLEN;
      Ash[n2] = -__expf(A_log[n2]);
    }
  }
  __syncthreads();
  bool fastA = true;
  #pragma unroll
  for (int n = 0; n < 16; n++) fastA = fastA && (fabsf(Ash[n] + (float)(n + 1)) < 1e-4f * (n + 1));
  float dw = dt_w[d], db = dt_b[d];
  float h[16];
  float S = 0.f;
  #pragma unroll
  for (int n = 0; n < 16; n++) h[n] = 0.f;
  for (int t = 0; t < CLEN; t++) {
    float delta = softplus_f(drs[t] * dw + db);
    S += delta;
    float xv = bf2f(xs_bf[(size_t)(c * CLEN + t) * D_INNER + d]);
    float w = delta * xv;
    float bb[16];
    *(float4*)&bb[0]  = *(const float4*)&Bsh[t][0];
    *(float4*)&bb[4]  = *(const float4*)&Bsh[t][4];
    *(float4*)&bb[8]  = *(const float4*)&Bsh[t][8];
    *(float4*)&bb[12] = *(const float4*)&Bsh[t][12];
    if (fastA) {
      float da[16];
      dapow(__expf(-delta), da);
      #pragma unroll
      for (int n = 0; n < 16; n++) h[n] = da[n] * h[n] + w * bb[n];
    } else {
      #pragma unroll
      for (int n = 0; n < 16; n++) {
        float da = __expf(delta * Ash[n]);
        h[n] = da * h[n] + w * bb[n];
      }
    }
  }
  size_t base = ((size_t)c * D_INNER + d) * 16;
  #pragma unroll
  for (int n = 0; n < 16; n += 4)
    *(float4*)&Hp[base + n] = make_float4(h[n], h[n + 1], h[n + 2], h[n + 3]);
  Sd[(size_t)c * D_INNER + d] = S;
}

// ---------------- scan combine ----------------
__global__ __launch_bounds__(256) void scan_combine(const float* __restrict__ Hp,
                                                    const float* __restrict__ Sd,
                                                    const float* __restrict__ A_log,
                                                    float* __restrict__ Hin) {
  int idx = blockIdx.x * 256 + threadIdx.x;
  int d = idx >> 4, n = idx & 15;
  float An = -__expf(A_log[n]);
  float h = 0.f;
  const size_t stride = (size_t)D_INNER * 16;
  #pragma unroll 8
  for (int c = 0; c < NCHUNK; c++) {
    float S  = Sd[(size_t)c * D_INNER + d];
    float hp = Hp[(size_t)c * stride + idx];
    Hin[(size_t)c * stride + idx] = h;
    h = __expf(An * S) * h + hp;
  }
}

// ---------------- scan pass2 + gating -> y_bf ----------------
__global__ __launch_bounds__(256) void scan_pass2(const ushort_t* __restrict__ xs_bf,
                                                  const float* __restrict__ xp,
                                                  const ushort_t* __restrict__ xz_bf,
                                                  const float* __restrict__ dt_w,
                                                  const float* __restrict__ dt_b,
                                                  const float* __restrict__ A_log,
                                                  const float* __restrict__ Dp,
                                                  const float* __restrict__ Hin,
                                                  ushort_t* __restrict__ y_bf) {
  int c = blockIdx.x, g = blockIdx.y;
  int d = g * 256 + threadIdx.x;
  __shared__ float Bsh[CLEN][16], Csh[CLEN][16], drs[CLEN], Ash[16];
  {
    int t = threadIdx.x >> 4, n = threadIdx.x & 15;
    Bsh[t][n] = xp[(size_t)(c * CLEN + t) * 33 + 1 + n];
    Csh[t][n] = xp[(size_t)(c * CLEN + t) * 33 + 17 + n];
    if (threadIdx.x < CLEN) drs[threadIdx.x] = xp[(size_t)(c * CLEN + threadIdx.x) * 33];
    else if (threadIdx.x < CLEN + 16) {
      int n2 = threadIdx.x - CLEN;
      Ash[n2] = -__expf(A_log[n2]);
    }
  }
  __syncthreads();
  bool fastA = true;
  #pragma unroll
  for (int n = 0; n < 16; n++) fastA = fastA && (fabsf(Ash[n] + (float)(n + 1)) < 1e-4f * (n + 1));
  float dw = dt_w[d], db = dt_b[d], Dd = Dp[d];
  float h[16];
  size_t hbase = ((size_t)c * D_INNER + d) * 16;
  #pragma unroll
  for (int n = 0; n < 16; n += 4)
    *(float4*)&h[n] = *(const float4*)&Hin[hbase + n];
  for (int t = 0; t < CLEN; t++) {
    float delta = softplus_f(drs[t] * dw + db);
    size_t ti = (size_t)(c * CLEN + t);
    float xv = bf2f(xs_bf[ti * D_INNER + d]);
    float w = delta * xv;
    float bb[16], cc[16];
    *(float4*)&bb[0]  = *(const float4*)&Bsh[t][0];
    *(float4*)&bb[4]  = *(const float4*)&Bsh[t][4];
    *(float4*)&bb[8]  = *(const float4*)&Bsh[t][8];
    *(float4*)&bb[12] = *(const float4*)&Bsh[t][12];
    *(float4*)&cc[0]  = *(const float4*)&Csh[t][0];
    *(float4*)&cc[4]  = *(const float4*)&Csh[t][4];
    *(float4*)&cc[8]  = *(const float4*)&Csh[t][8];
    *(float4*)&cc[12] = *(const float4*)&Csh[t][12];
    float y = 0.f;
    if (fastA) {
      float da[16];
      dapow(__expf(-delta), da);
      #pragma unroll
      for (int n = 0; n < 16; n++) {
        h[n] = da[n] * h[n] + w * bb[n];
        y += h[n] * cc[n];
      }
    } else {
      #pragma unroll
      for (int n = 0; n < 16; n++) {
        float da = __expf(delta * Ash[n]);
        h[n] = da * h[n] + w * bb[n];
        y += h[n] * cc[n];
      }
    }
    float z = bf2f(xz_bf[ti * (2 * D_INNER) + D_INNER + d]);
    float sz = z / (1.f + __expf(-z));
    float out = (y + xv * Dd) * sz;
    y_bf[ti * D_INNER + d] = f2bf(out);
  }
}

// ---------------- launch ----------------
extern "C" void kernel_launch(void* const* d_in, const int* in_sizes, int n_in,
                              void* d_out, int out_size, void* d_ws, size_t ws_size,
                              hipStream_t stream) {
  const float* x      = (const float*)d_in[0];
  const float* ln_g   = (const float*)d_in[1];
  const float* ln_b   = (const float*)d_in[2];
  const float* in_w   = (const float*)d_in[3];
  const float* conv_w = (const float*)d_in[4];
  const float* conv_b = (const float*)d_in[5];
  const float* xproj_w= (const float*)d_in[6];
  const float* dt_w   = (const float*)d_in[7];
  const float* dt_b   = (const float*)d_in[8];
  const float* A_log  = (const float*)d_in[9];
  const float* Dp     = (const float*)d_in[10];
  const float* out_w  = (const float*)d_in[11];
  float* out = (float*)d_out;

  char* ws = (char*)d_ws;
  size_t off = 0;
  auto alloc = [&](size_t bytes) { char* p = ws + off; off += (bytes + 255) & ~(size_t)255; return p; };
  ushort_t* xz_bf   = (ushort_t*)alloc((size_t)SEQ * 2 * D_INNER * 2);
  ushort_t* xn_bf   = (ushort_t*)alloc((size_t)SEQ * D_MODEL * 2);
  ushort_t* inw_bf  = (ushort_t*)alloc((size_t)2 * D_INNER * D_MODEL * 2);
  ushort_t* outw_bf = (ushort_t*)alloc((size_t)D_MODEL * D_INNER * 2);
  ushort_t* xs_bf   = (ushort_t*)alloc((size_t)SEQ * D_INNER * 2);
  float*    xp      = (float*)   alloc((size_t)SEQ * 33 * 4);
  float*    Hp      = (float*)   alloc((size_t)NCHUNK * D_INNER * 16 * 4);
  float*    Hin     = (float*)   alloc((size_t)NCHUNK * D_INNER * 16 * 4);
  float*    Sd      = (float*)   alloc((size_t)NCHUNK * D_INNER * 4);
  ushort_t* y_bf    = (ushort_t*)alloc((size_t)SEQ * D_INNER * 2);
  (void)ws_size;

  cvt_w_kernel<<<(2 * D_INNER * D_MODEL + D_MODEL * D_INNER + 255) / 256, 256, 0, stream>>>(
      in_w, out_w, inw_bf, outw_bf);
  ln_kernel<<<SEQ, 256, 0, stream>>>(x, ln_g, ln_b, xn_bf);
  // in_proj: xz = xn @ in_w^T  (M=2048, N=4096, K=1024), pipelined
  gemm_pipe<D_MODEL><<<dim3(2 * D_INNER / 128, SEQ / 256), 256, 0, stream>>>(
      xn_bf, inw_bf, xz_bf, SEQ, 2 * D_INNER);
  // conv + silu + x_proj
  convxp_kernel<<<SEQ / 4, 256, 0, stream>>>(xz_bf, conv_w, conv_b, xproj_w, xs_bf, xp);
  // scan
  scan_pass1<<<dim3(NCHUNK, D_INNER / 256), 256, 0, stream>>>(xs_bf, xp, dt_w, dt_b, A_log, Hp, Sd);
  scan_combine<<<D_INNER * 16 / 256, 256, 0, stream>>>(Hp, Sd, A_log, Hin);
  scan_pass2<<<dim3(NCHUNK, D_INNER / 256), 256, 0, stream>>>(xs_bf, xp, xz_bf, dt_w, dt_b, A_log,
                                                              Dp, Hin, y_bf);
  // out_proj + residual  (M=2048, N=1024, K=2048)
  gemm_bt<64, 128><<<dim3(D_MODEL / 128, SEQ / 64), 256, 0, stream>>>(
      y_bf, outw_bf, out, x, SEQ, D_MODEL, D_INNER);
}

// Round 4
// 153.082 us; speedup vs baseline: 1.3668x; 1.2310x over previous
//
#include <hip/hip_runtime.h>
#include <cstdint>
#include <cstddef>

#define D_MODEL 1024
#define D_STATE 16
#define D_CONV  4
#define D_INNER 2048
#define SEQ     2048
#define NCHUNK  128
#define CLEN    16
#define LN_EPS  1e-5f

typedef unsigned short ushort_t;
typedef __attribute__((ext_vector_type(8))) short short8;
typedef __attribute__((ext_vector_type(4))) float f32x4;

__device__ __forceinline__ ushort_t f2bf(float x) {
  union { float f; uint32_t u; } v; v.f = x;
  uint32_t r = (v.u + 0x7fffu + ((v.u >> 16) & 1u)) >> 16;
  return (ushort_t)r;
}
__device__ __forceinline__ float bf2f(ushort_t u) {
  union { uint32_t x; float f; } v; v.x = ((uint32_t)u) << 16; return v.f;
}

__device__ __forceinline__ void async16(void* lds, const void* g) {
  __builtin_amdgcn_global_load_lds(
      (const __attribute__((address_space(1))) unsigned int*)g,
      (__attribute__((address_space(3))) unsigned int*)lds, 16, 0, 0);
}

__device__ __forceinline__ float softplus_f(float x) {
  if (x > 20.f) return x;
  if (x < -20.f) return __expf(x);
  return __logf(1.f + __expf(x));
}

// ---------------- weight conversion (f32 -> bf16), incl. padded xproj ----------------
__global__ void cvt_w_kernel(const float* __restrict__ inw,
                             const float* __restrict__ outw,
                             const float* __restrict__ xpw,
                             ushort_t* __restrict__ inw_bf,
                             ushort_t* __restrict__ outw_bf,
                             ushort_t* __restrict__ xpw_bf) {
  int idx = blockIdx.x * 256 + threadIdx.x;
  const int n1 = 2 * D_INNER * D_MODEL;
  const int n2 = D_MODEL * D_INNER;
  const int n3 = 64 * D_INNER;          // xproj padded to 64 rows
  if (idx < n1) {
    inw_bf[idx] = f2bf(inw[idx]);
  } else if (idx < n1 + n2) {
    int j = idx - n1;
    outw_bf[j] = f2bf(outw[j]);
  } else if (idx < n1 + n2 + n3) {
    int j = idx - n1 - n2;
    xpw_bf[j] = (j < 33 * D_INNER) ? f2bf(xpw[j]) : (ushort_t)0;
  }
}

// ---------------- LayerNorm -> bf16 ----------------
__global__ __launch_bounds__(256) void ln_kernel(const float* __restrict__ x,
                                                 const float* __restrict__ g,
                                                 const float* __restrict__ b,
                                                 ushort_t* __restrict__ xn_bf) {
  int row = blockIdx.x;
  const float4* xr = (const float4*)(x + (size_t)row * D_MODEL);
  float4 v = xr[threadIdx.x];
  float s  = v.x + v.y + v.z + v.w;
  float ss = v.x * v.x + v.y * v.y + v.z * v.z + v.w * v.w;
  #pragma unroll
  for (int o = 32; o; o >>= 1) { s += __shfl_down(s, o); ss += __shfl_down(ss, o); }
  __shared__ float sbuf[8], ssbuf[8];
  int wid = threadIdx.x >> 6, lane = threadIdx.x & 63;
  if (lane == 0) { sbuf[wid] = s; ssbuf[wid] = ss; }
  __syncthreads();
  if (threadIdx.x == 0) {
    float t = 0.f, t2 = 0.f;
    for (int i = 0; i < 4; i++) { t += sbuf[i]; t2 += ssbuf[i]; }
    float mu = t / D_MODEL;
    sbuf[4] = mu;
    ssbuf[4] = rsqrtf(t2 / D_MODEL - mu * mu + LN_EPS);
  }
  __syncthreads();
  float mu = sbuf[4], inv = ssbuf[4];
  float4 gv = ((const float4*)g)[threadIdx.x];
  float4 bv = ((const float4*)b)[threadIdx.x];
  ushort_t o4[4];
  o4[0] = f2bf((v.x - mu) * inv * gv.x + bv.x);
  o4[1] = f2bf((v.y - mu) * inv * gv.y + bv.y);
  o4[2] = f2bf((v.z - mu) * inv * gv.z + bv.z);
  o4[3] = f2bf((v.w - mu) * inv * gv.w + bv.w);
  *(ushort4*)&xn_bf[(size_t)row * D_MODEL + threadIdx.x * 4] =
      make_ushort4(o4[0], o4[1], o4[2], o4[3]);
}

// ---------------- unified pipelined MFMA GEMM, NT layout ----------------
// BK=32, triple-buffered LDS, counted vmcnt (BEFORE barrier), 4 waves (2x2),
// XOR LDS swizzle pre-applied on global src. EPI: 0=bf16 out, 1=f32+residual,
// 2=xp f32 (stride 33, cols<33 only).
template <int BM, int BN, int KDIM, int EPI>
__global__ __launch_bounds__(256, 2) void gemm_pipe(const ushort_t* __restrict__ A,
                                                    const ushort_t* __restrict__ B,
                                                    void* __restrict__ Cout,
                                                    const float* __restrict__ R,
                                                    int N) {
  constexpr int NT = KDIM / 32;
  constexpr int K2 = KDIM * 2;          // row stride bytes
  constexpr int IA = BM / 64;           // staging issues per wave per tile
  constexpr int IB = BN / 64;
  constexpr int S  = IA + IB;           // issues per thread per tile
  constexpr int WTM = BM / 2, WTN = BN / 2;
  constexpr int MREP = WTM / 16, NREP = WTN / 16;
  __shared__ __align__(16) ushort_t As[3][BM * 32];
  __shared__ __align__(16) ushort_t Bs[3][BN * 32];

  const int nwg = gridDim.x * gridDim.y;
  int bid = blockIdx.y * gridDim.x + blockIdx.x;
  int swz = (bid & 7) * (nwg >> 3) + (bid >> 3);
  const int bn = swz % gridDim.x, bm = swz / gridDim.x;
  const int tid = threadIdx.x, wid = tid >> 6, lane = tid & 63;
  const int wm = wid >> 1, wn = wid & 1;
  const int row0A = bm * BM, row0B = bn * BN;

  const char* gA[IA];
  const char* gB[IB];
  #pragma unroll
  for (int i = 0; i < IA; i++) {
    int o = i * 4096 + tid * 16;
    int r = o >> 6, src = (o & 63) ^ ((r & 3) << 4);
    gA[i] = (const char*)A + (size_t)(row0A + r) * K2 + src;
  }
  #pragma unroll
  for (int i = 0; i < IB; i++) {
    int o = i * 4096 + tid * 16;
    int r = o >> 6, src = (o & 63) ^ ((r & 3) << 4);
    gB[i] = (const char*)B + (size_t)(row0B + r) * K2 + src;
  }
  const int ldsW = wid * 1024;

  auto STAGE = [&](int b, int kt) {
    int kb = kt * 64;
    #pragma unroll
    for (int i = 0; i < IA; i++)
      async16((char*)&As[b][0] + i * 4096 + ldsW, gA[i] + kb);
    #pragma unroll
    for (int i = 0; i < IB; i++)
      async16((char*)&Bs[b][0] + i * 4096 + ldsW, gB[i] + kb);
  };

  STAGE(0, 0);
  STAGE(1, 1);

  int offA[MREP], offB[NREP];
  #pragma unroll
  for (int m = 0; m < MREP; m++) {
    int row = wm * WTM + m * 16 + (lane & 15);
    offA[m] = row * 64 + ((((lane >> 4)) ^ (row & 3)) << 4);
  }
  #pragma unroll
  for (int n = 0; n < NREP; n++) {
    int row = wn * WTN + n * 16 + (lane & 15);
    offB[n] = row * 64 + ((((lane >> 4)) ^ (row & 3)) << 4);
  }

  f32x4 acc[MREP][NREP] = {};
  int cur = 0;
  for (int kt = 0; kt < NT; kt++) {
    // wait OUR tile-kt staging loads, THEN barrier => all waves' tile-kt landed
    if (kt < NT - 1) {
      if constexpr (S == 6)      asm volatile("s_waitcnt vmcnt(6)" ::: "memory");
      else if constexpr (S == 4) asm volatile("s_waitcnt vmcnt(4)" ::: "memory");
      else if constexpr (S == 3) asm volatile("s_waitcnt vmcnt(3)" ::: "memory");
      else                       asm volatile("s_waitcnt vmcnt(2)" ::: "memory");
    } else {
      asm volatile("s_waitcnt vmcnt(0)" ::: "memory");
    }
    __builtin_amdgcn_s_barrier();
    __builtin_amdgcn_sched_barrier(0);
    const char* Ab = (const char*)&As[cur][0];
    const char* Bb = (const char*)&Bs[cur][0];
    short8 af[MREP], bf[NREP];
    #pragma unroll
    for (int m = 0; m < MREP; m++) af[m] = *(const short8*)(Ab + offA[m]);
    #pragma unroll
    for (int n = 0; n < NREP; n++) bf[n] = *(const short8*)(Bb + offB[n]);
    if (kt + 2 < NT) {
      int b2 = cur + 2; if (b2 >= 3) b2 -= 3;
      STAGE(b2, kt + 2);
    }
    __builtin_amdgcn_s_setprio(1);
    #pragma unroll
    for (int m = 0; m < MREP; m++)
      #pragma unroll
      for (int n = 0; n < NREP; n++)
        acc[m][n] = __builtin_amdgcn_mfma_f32_16x16x32_bf16(af[m], bf[n], acc[m][n], 0, 0, 0);
    __builtin_amdgcn_s_setprio(0);
    cur++; if (cur == 3) cur = 0;
  }

  #pragma unroll
  for (int m = 0; m < MREP; m++)
    #pragma unroll
    for (int n = 0; n < NREP; n++) {
      int r0 = row0A + wm * WTM + m * 16 + ((lane >> 4) << 2);
      int c  = row0B + wn * WTN + n * 16 + (lane & 15);
      #pragma unroll
      for (int q = 0; q < 4; q++) {
        if constexpr (EPI == 0) {
          ((ushort_t*)Cout)[(size_t)(r0 + q) * N + c] = f2bf(acc[m][n][q]);
        } else if constexpr (EPI == 1) {
          size_t idx = (size_t)(r0 + q) * N + c;
          ((float*)Cout)[idx] = acc[m][n][q] + R[idx];
        } else {
          if (c < 33) ((float*)Cout)[(size_t)(r0 + q) * 33 + c] = acc[m][n][q];
        }
      }
    }
}

// ---------------- depthwise causal conv + SiLU (elementwise) ----------------
__global__ __launch_bounds__(256) void conv_silu_kernel(const ushort_t* __restrict__ xz_bf,
                                                        const float* __restrict__ cw,
                                                        const float* __restrict__ cb,
                                                        ushort_t* __restrict__ xs_bf) {
  const int t = blockIdx.x;
  const int d0 = threadIdx.x * 8;
  short8 rows[4];
  #pragma unroll
  for (int k = 0; k < 4; k++) {
    int tt = t - 3 + k;
    if (tt >= 0) rows[k] = *(const short8*)&xz_bf[(size_t)tt * (2 * D_INNER) + d0];
    else         rows[k] = (short8)0;
  }
  short8 o8;
  #pragma unroll
  for (int j = 0; j < 8; j++) {
    float4 w = ((const float4*)cw)[d0 + j];
    float acc = cb[d0 + j]
              + bf2f((ushort_t)rows[0][j]) * w.x
              + bf2f((ushort_t)rows[1][j]) * w.y
              + bf2f((ushort_t)rows[2][j]) * w.z
              + bf2f((ushort_t)rows[3][j]) * w.w;
    float sg = 1.f / (1.f + __expf(-acc));
    o8[j] = (short)f2bf(acc * sg);
  }
  *(short8*)&xs_bf[(size_t)t * D_INNER + d0] = o8;
}

// da[n] = g1^(n+1), log-depth
__device__ __forceinline__ void dapow(float g1, float* da) {
  float g2 = g1 * g1, g4 = g2 * g2, g8 = g4 * g4;
  #pragma unroll
  for (int n = 0; n < 16; n++) {
    int e = n + 1;
    float v = (e & 1) ? g1 : 1.f;
    if (e & 2) v *= g2;
    if (e & 4) v *= g4;
    if (e & 8) v *= g8;
    da[n] = v;
  }
}

// ---------------- scan pass1 ----------------
__global__ __launch_bounds__(256) void scan_pass1(const ushort_t* __restrict__ xs_bf,
                                                  const float* __restrict__ xp,
                                                  const float* __restrict__ dt_w,
                                                  const float* __restrict__ dt_b,
                                                  const float* __restrict__ A_log,
                                                  float* __restrict__ Hp,
                                                  float* __restrict__ Sd) {
  int c = blockIdx.x, g = blockIdx.y;
  int d = g * 256 + threadIdx.x;
  __shared__ float Bsh[CLEN][16], drs[CLEN], Ash[16];
  {
    int t = threadIdx.x >> 4, n = threadIdx.x & 15;
    Bsh[t][n] = xp[(size_t)(c * CLEN + t) * 33 + 1 + n];
    if (threadIdx.x < CLEN) drs[threadIdx.x] = xp[(size_t)(c * CLEN + threadIdx.x) * 33];
    else if (threadIdx.x < CLEN + 16) {
      int n2 = threadIdx.x - CLEN;
      Ash[n2] = -__expf(A_log[n2]);
    }
  }
  __syncthreads();
  bool fastA = true;
  #pragma unroll
  for (int n = 0; n < 16; n++) fastA = fastA && (fabsf(Ash[n] + (float)(n + 1)) < 1e-4f * (n + 1));
  float dw = dt_w[d], db = dt_b[d];
  float h[16];
  float S = 0.f;
  #pragma unroll
  for (int n = 0; n < 16; n++) h[n] = 0.f;
  for (int t = 0; t < CLEN; t++) {
    float delta = softplus_f(drs[t] * dw + db);
    S += delta;
    float xv = bf2f(xs_bf[(size_t)(c * CLEN + t) * D_INNER + d]);
    float w = delta * xv;
    float bb[16];
    *(float4*)&bb[0]  = *(const float4*)&Bsh[t][0];
    *(float4*)&bb[4]  = *(const float4*)&Bsh[t][4];
    *(float4*)&bb[8]  = *(const float4*)&Bsh[t][8];
    *(float4*)&bb[12] = *(const float4*)&Bsh[t][12];
    if (fastA) {
      float da[16];
      dapow(__expf(-delta), da);
      #pragma unroll
      for (int n = 0; n < 16; n++) h[n] = da[n] * h[n] + w * bb[n];
    } else {
      #pragma unroll
      for (int n = 0; n < 16; n++) {
        float da = __expf(delta * Ash[n]);
        h[n] = da * h[n] + w * bb[n];
      }
    }
  }
  size_t base = ((size_t)c * D_INNER + d) * 16;
  #pragma unroll
  for (int n = 0; n < 16; n += 4)
    *(float4*)&Hp[base + n] = make_float4(h[n], h[n + 1], h[n + 2], h[n + 3]);
  Sd[(size_t)c * D_INNER + d] = S;
}

// ---------------- scan combine ----------------
__global__ __launch_bounds__(256) void scan_combine(const float* __restrict__ Hp,
                                                    const float* __restrict__ Sd,
                                                    const float* __restrict__ A_log,
                                                    float* __restrict__ Hin) {
  int idx = blockIdx.x * 256 + threadIdx.x;
  int d = idx >> 4, n = idx & 15;
  float An = -__expf(A_log[n]);
  float h = 0.f;
  const size_t stride = (size_t)D_INNER * 16;
  #pragma unroll 8
  for (int c = 0; c < NCHUNK; c++) {
    float S  = Sd[(size_t)c * D_INNER + d];
    float hp = Hp[(size_t)c * stride + idx];
    Hin[(size_t)c * stride + idx] = h;
    h = __expf(An * S) * h + hp;
  }
}

// ---------------- scan pass2 + gating -> y_bf ----------------
__global__ __launch_bounds__(256) void scan_pass2(const ushort_t* __restrict__ xs_bf,
                                                  const float* __restrict__ xp,
                                                  const ushort_t* __restrict__ xz_bf,
                                                  const float* __restrict__ dt_w,
                                                  const float* __restrict__ dt_b,
                                                  const float* __restrict__ A_log,
                                                  const float* __restrict__ Dp,
                                                  const float* __restrict__ Hin,
                                                  ushort_t* __restrict__ y_bf) {
  int c = blockIdx.x, g = blockIdx.y;
  int d = g * 256 + threadIdx.x;
  __shared__ float Bsh[CLEN][16], Csh[CLEN][16], drs[CLEN], Ash[16];
  {
    int t = threadIdx.x >> 4, n = threadIdx.x & 15;
    Bsh[t][n] = xp[(size_t)(c * CLEN + t) * 33 + 1 + n];
    Csh[t][n] = xp[(size_t)(c * CLEN + t) * 33 + 17 + n];
    if (threadIdx.x < CLEN) drs[threadIdx.x] = xp[(size_t)(c * CLEN + threadIdx.x) * 33];
    else if (threadIdx.x < CLEN + 16) {
      int n2 = threadIdx.x - CLEN;
      Ash[n2] = -__expf(A_log[n2]);
    }
  }
  __syncthreads();
  bool fastA = true;
  #pragma unroll
  for (int n = 0; n < 16; n++) fastA = fastA && (fabsf(Ash[n] + (float)(n + 1)) < 1e-4f * (n + 1));
  float dw = dt_w[d], db = dt_b[d], Dd = Dp[d];
  float h[16];
  size_t hbase = ((size_t)c * D_INNER + d) * 16;
  #pragma unroll
  for (int n = 0; n < 16; n += 4)
    *(float4*)&h[n] = *(const float4*)&Hin[hbase + n];
  for (int t = 0; t < CLEN; t++) {
    float delta = softplus_f(drs[t] * dw + db);
    size_t ti = (size_t)(c * CLEN + t);
    float xv = bf2f(xs_bf[ti * D_INNER + d]);
    float w = delta * xv;
    float bb[16], cc[16];
    *(float4*)&bb[0]  = *(const float4*)&Bsh[t][0];
    *(float4*)&bb[4]  = *(const float4*)&Bsh[t][4];
    *(float4*)&bb[8]  = *(const float4*)&Bsh[t][8];
    *(float4*)&bb[12] = *(const float4*)&Bsh[t][12];
    *(float4*)&cc[0]  = *(const float4*)&Csh[t][0];
    *(float4*)&cc[4]  = *(const float4*)&Csh[t][4];
    *(float4*)&cc[8]  = *(const float4*)&Csh[t][8];
    *(float4*)&cc[12] = *(const float4*)&Csh[t][12];
    float y = 0.f;
    if (fastA) {
      float da[16];
      dapow(__expf(-delta), da);
      #pragma unroll
      for (int n = 0; n < 16; n++) {
        h[n] = da[n] * h[n] + w * bb[n];
        y += h[n] * cc[n];
      }
    } else {
      #pragma unroll
      for (int n = 0; n < 16; n++) {
        float da = __expf(delta * Ash[n]);
        h[n] = da * h[n] + w * bb[n];
        y += h[n] * cc[n];
      }
    }
    float z = bf2f(xz_bf[ti * (2 * D_INNER) + D_INNER + d]);
    float sz = z / (1.f + __expf(-z));
    float out = (y + xv * Dd) * sz;
    y_bf[ti * D_INNER + d] = f2bf(out);
  }
}

// ---------------- launch ----------------
extern "C" void kernel_launch(void* const* d_in, const int* in_sizes, int n_in,
                              void* d_out, int out_size, void* d_ws, size_t ws_size,
                              hipStream_t stream) {
  const float* x      = (const float*)d_in[0];
  const float* ln_g   = (const float*)d_in[1];
  const float* ln_b   = (const float*)d_in[2];
  const float* in_w   = (const float*)d_in[3];
  const float* conv_w = (const float*)d_in[4];
  const float* conv_b = (const float*)d_in[5];
  const float* xproj_w= (const float*)d_in[6];
  const float* dt_w   = (const float*)d_in[7];
  const float* dt_b   = (const float*)d_in[8];
  const float* A_log  = (const float*)d_in[9];
  const float* Dp     = (const float*)d_in[10];
  const float* out_w  = (const float*)d_in[11];
  float* out = (float*)d_out;

  char* ws = (char*)d_ws;
  size_t off = 0;
  auto alloc = [&](size_t bytes) { char* p = ws + off; off += (bytes + 255) & ~(size_t)255; return p; };
  ushort_t* xz_bf   = (ushort_t*)alloc((size_t)SEQ * 2 * D_INNER * 2);
  ushort_t* xn_bf   = (ushort_t*)alloc((size_t)SEQ * D_MODEL * 2);
  ushort_t* inw_bf  = (ushort_t*)alloc((size_t)2 * D_INNER * D_MODEL * 2);
  ushort_t* outw_bf = (ushort_t*)alloc((size_t)D_MODEL * D_INNER * 2);
  ushort_t* xpw_bf  = (ushort_t*)alloc((size_t)64 * D_INNER * 2);
  ushort_t* xs_bf   = (ushort_t*)alloc((size_t)SEQ * D_INNER * 2);
  float*    xp      = (float*)   alloc((size_t)SEQ * 33 * 4);
  float*    Hp      = (float*)   alloc((size_t)NCHUNK * D_INNER * 16 * 4);
  float*    Hin     = (float*)   alloc((size_t)NCHUNK * D_INNER * 16 * 4);
  float*    Sd      = (float*)   alloc((size_t)NCHUNK * D_INNER * 4);
  ushort_t* y_bf    = (ushort_t*)alloc((size_t)SEQ * D_INNER * 2);
  (void)ws_size;

  const int ncvt = 2 * D_INNER * D_MODEL + D_MODEL * D_INNER + 64 * D_INNER;
  cvt_w_kernel<<<(ncvt + 255) / 256, 256, 0, stream>>>(
      in_w, out_w, xproj_w, inw_bf, outw_bf, xpw_bf);
  ln_kernel<<<SEQ, 256, 0, stream>>>(x, ln_g, ln_b, xn_bf);
  // in_proj: M=2048 N=4096 K=1024
  gemm_pipe<256, 128, D_MODEL, 0><<<dim3(2 * D_INNER / 128, SEQ / 256), 256, 0, stream>>>(
      xn_bf, inw_bf, xz_bf, nullptr, 2 * D_INNER);
  // conv + silu
  conv_silu_kernel<<<SEQ, 256, 0, stream>>>(xz_bf, conv_w, conv_b, xs_bf);
  // x_proj: M=2048 N=64(pad) K=2048 -> xp[2048][33]
  gemm_pipe<64, 64, D_INNER, 2><<<dim3(1, SEQ / 64), 256, 0, stream>>>(
      xs_bf, xpw_bf, xp, nullptr, 64);
  // scan
  scan_pass1<<<dim3(NCHUNK, D_INNER / 256), 256, 0, stream>>>(xs_bf, xp, dt_w, dt_b, A_log, Hp, Sd);
  scan_combine<<<D_INNER * 16 / 256, 256, 0, stream>>>(Hp, Sd, A_log, Hin);
  scan_pass2<<<dim3(NCHUNK, D_INNER / 256), 256, 0, stream>>>(xs_bf, xp, xz_bf, dt_w, dt_b, A_log,
                                                              Dp, Hin, y_bf);
  // out_proj + residual: M=2048 N=1024 K=2048
  gemm_pipe<128, 64, D_INNER, 1><<<dim3(D_MODEL / 64, SEQ / 128), 256, 0, stream>>>(
      y_bf, outw_bf, out, x, D_MODEL);
}

// Round 5
// 140.010 us; speedup vs baseline: 1.4944x; 1.0934x over previous
//
#include <hip/hip_runtime.h>
#include <cstdint>
#include <cstddef>

#define D_MODEL 1024
#define D_STATE 16
#define D_CONV  4
#define D_INNER 2048
#define SEQ     2048
#define NCHUNK  128
#define CLEN    16
#define LN_EPS  1e-5f

typedef unsigned short ushort_t;
typedef __attribute__((ext_vector_type(8))) short short8;
typedef __attribute__((ext_vector_type(4))) float f32x4;

__device__ __forceinline__ ushort_t f2bf(float x) {
  union { float f; uint32_t u; } v; v.f = x;
  uint32_t r = (v.u + 0x7fffu + ((v.u >> 16) & 1u)) >> 16;
  return (ushort_t)r;
}
__device__ __forceinline__ float bf2f(ushort_t u) {
  union { uint32_t x; float f; } v; v.x = ((uint32_t)u) << 16; return v.f;
}

__device__ __forceinline__ void async16(void* lds, const void* g) {
  __builtin_amdgcn_global_load_lds(
      (const __attribute__((address_space(1))) unsigned int*)g,
      (__attribute__((address_space(3))) unsigned int*)lds, 16, 0, 0);
}

__device__ __forceinline__ float softplus_f(float x) {
  if (x > 20.f) return x;
  if (x < -20.f) return __expf(x);
  return __logf(1.f + __expf(x));
}

// ---------------- prep: weight cvt (f32->bf16) + LayerNorm, one kernel ----------------
__global__ __launch_bounds__(256) void prep_kernel(const float* __restrict__ x,
                                                   const float* __restrict__ g,
                                                   const float* __restrict__ b,
                                                   const float* __restrict__ inw,
                                                   const float* __restrict__ outw,
                                                   const float* __restrict__ xpw,
                                                   ushort_t* __restrict__ xn_bf,
                                                   ushort_t* __restrict__ inw_bf,
                                                   ushort_t* __restrict__ outw_bf,
                                                   ushort_t* __restrict__ xpw_bf) {
  int blk = blockIdx.x;
  if (blk < SEQ) {
    // ---- LayerNorm row ----
    int row = blk;
    const float4* xr = (const float4*)(x + (size_t)row * D_MODEL);
    float4 v = xr[threadIdx.x];
    float s  = v.x + v.y + v.z + v.w;
    float ss = v.x * v.x + v.y * v.y + v.z * v.z + v.w * v.w;
    #pragma unroll
    for (int o = 32; o; o >>= 1) { s += __shfl_down(s, o); ss += __shfl_down(ss, o); }
    __shared__ float sbuf[8], ssbuf[8];
    int wid = threadIdx.x >> 6, lane = threadIdx.x & 63;
    if (lane == 0) { sbuf[wid] = s; ssbuf[wid] = ss; }
    __syncthreads();
    if (threadIdx.x == 0) {
      float t = 0.f, t2 = 0.f;
      for (int i = 0; i < 4; i++) { t += sbuf[i]; t2 += ssbuf[i]; }
      float mu = t / D_MODEL;
      sbuf[4] = mu;
      ssbuf[4] = rsqrtf(t2 / D_MODEL - mu * mu + LN_EPS);
    }
    __syncthreads();
    float mu = sbuf[4], inv = ssbuf[4];
    float4 gv = ((const float4*)g)[threadIdx.x];
    float4 bv = ((const float4*)b)[threadIdx.x];
    ushort_t o4[4];
    o4[0] = f2bf((v.x - mu) * inv * gv.x + bv.x);
    o4[1] = f2bf((v.y - mu) * inv * gv.y + bv.y);
    o4[2] = f2bf((v.z - mu) * inv * gv.z + bv.z);
    o4[3] = f2bf((v.w - mu) * inv * gv.w + bv.w);
    *(ushort4*)&xn_bf[(size_t)row * D_MODEL + threadIdx.x * 4] =
        make_ushort4(o4[0], o4[1], o4[2], o4[3]);
  } else {
    // ---- weight conversion ----
    int idx = (blk - SEQ) * 256 + threadIdx.x;
    const int n1 = 2 * D_INNER * D_MODEL;
    const int n2 = D_MODEL * D_INNER;
    const int n3 = 64 * D_INNER;
    if (idx < n1) {
      inw_bf[idx] = f2bf(inw[idx]);
    } else if (idx < n1 + n2) {
      int j = idx - n1;
      outw_bf[j] = f2bf(outw[j]);
    } else if (idx < n1 + n2 + n3) {
      int j = idx - n1 - n2;
      xpw_bf[j] = (j < 33 * D_INNER) ? f2bf(xpw[j]) : (ushort_t)0;
    }
  }
}

// ---------------- unified pipelined MFMA GEMM, NT layout ----------------
// BK=32, NBUF-deep LDS ring, counted vmcnt BEFORE barrier, 4 waves (2x2),
// XOR LDS swizzle pre-applied on global src.
// EPI: 0=bf16 out stride N, 1=f32+residual stride N, 3=f32 partial xp (stride 33).
// KSPLIT>1: gridDim.x indexes the K-split (N must be a single tile).
template <int BM, int BN, int KDIM, int EPI, int NBUF, int KSPLIT>
__global__ __launch_bounds__(256, 2) void gemm_pipe(const ushort_t* __restrict__ A,
                                                    const ushort_t* __restrict__ B,
                                                    void* __restrict__ Cout,
                                                    const float* __restrict__ R,
                                                    int N) {
  constexpr int KT = KDIM / 32 / KSPLIT;   // K-tiles per block
  constexpr int K2 = KDIM * 2;             // row stride bytes
  constexpr int IA = BM / 64, IB = BN / 64;
  constexpr int S  = IA + IB;              // staging issues per thread per tile
  constexpr int W  = (NBUF - 2) * S;       // in-flight issues allowed at wait
  constexpr int WTM = BM / 2, WTN = BN / 2;
  constexpr int MREP = WTM / 16, NREP = WTN / 16;
  __shared__ __align__(16) ushort_t As[NBUF][BM * 32];
  __shared__ __align__(16) ushort_t Bs[NBUF][BN * 32];

  const int nwg = gridDim.x * gridDim.y;
  int bid = blockIdx.y * gridDim.x + blockIdx.x;
  int swz = (bid & 7) * (nwg >> 3) + (bid >> 3);
  int bn = swz % gridDim.x, bm = swz / gridDim.x;
  int ks = 0;
  if constexpr (KSPLIT > 1) { ks = bn; bn = 0; }
  const int tid = threadIdx.x, wid = tid >> 6, lane = tid & 63;
  const int wm = wid >> 1, wn = wid & 1;
  const int row0A = bm * BM, row0B = bn * BN;
  const size_t kbase = (size_t)ks * KT * 64;   // byte offset into K

  const char* gA[IA];
  const char* gB[IB];
  #pragma unroll
  for (int i = 0; i < IA; i++) {
    int o = i * 4096 + tid * 16;
    int r = o >> 6, src = (o & 63) ^ ((r & 3) << 4);
    gA[i] = (const char*)A + (size_t)(row0A + r) * K2 + src + kbase;
  }
  #pragma unroll
  for (int i = 0; i < IB; i++) {
    int o = i * 4096 + tid * 16;
    int r = o >> 6, src = (o & 63) ^ ((r & 3) << 4);
    gB[i] = (const char*)B + (size_t)(row0B + r) * K2 + src + kbase;
  }
  const int ldsW = wid * 1024;

  auto STAGE = [&](int bb, int kt) {
    int kb = kt * 64;
    #pragma unroll
    for (int i = 0; i < IA; i++)
      async16((char*)&As[bb][0] + i * 4096 + ldsW, gA[i] + kb);
    #pragma unroll
    for (int i = 0; i < IB; i++)
      async16((char*)&Bs[bb][0] + i * 4096 + ldsW, gB[i] + kb);
  };

  #pragma unroll
  for (int p = 0; p < NBUF - 1; p++) STAGE(p, p);

  int offA[MREP], offB[NREP];
  #pragma unroll
  for (int m = 0; m < MREP; m++) {
    int row = wm * WTM + m * 16 + (lane & 15);
    offA[m] = row * 64 + ((((lane >> 4)) ^ (row & 3)) << 4);
  }
  #pragma unroll
  for (int n = 0; n < NREP; n++) {
    int row = wn * WTN + n * 16 + (lane & 15);
    offB[n] = row * 64 + ((((lane >> 4)) ^ (row & 3)) << 4);
  }

  f32x4 acc[MREP][NREP] = {};
  int cur = 0;
  for (int kt = 0; kt < KT; kt++) {
    // wait for OUR tile-kt loads, THEN barrier => all waves' tile-kt landed
    if (kt < KT - 1) {
      if constexpr (W == 6)       asm volatile("s_waitcnt vmcnt(6)" ::: "memory");
      else if constexpr (W == 8)  asm volatile("s_waitcnt vmcnt(8)" ::: "memory");
      else if constexpr (W == 12) asm volatile("s_waitcnt vmcnt(12)" ::: "memory");
      else                        asm volatile("s_waitcnt vmcnt(0)" ::: "memory");
    } else {
      asm volatile("s_waitcnt vmcnt(0)" ::: "memory");
    }
    __builtin_amdgcn_s_barrier();
    __builtin_amdgcn_sched_barrier(0);
    const char* Ab = (const char*)&As[cur][0];
    const char* Bb = (const char*)&Bs[cur][0];
    short8 af[MREP], bf[NREP];
    #pragma unroll
    for (int m = 0; m < MREP; m++) af[m] = *(const short8*)(Ab + offA[m]);
    #pragma unroll
    for (int n = 0; n < NREP; n++) bf[n] = *(const short8*)(Bb + offB[n]);
    if (kt + NBUF - 1 < KT) {
      int b2 = cur + NBUF - 1; if (b2 >= NBUF) b2 -= NBUF;
      STAGE(b2, kt + NBUF - 1);
    }
    __builtin_amdgcn_s_setprio(1);
    #pragma unroll
    for (int m = 0; m < MREP; m++)
      #pragma unroll
      for (int n = 0; n < NREP; n++)
        acc[m][n] = __builtin_amdgcn_mfma_f32_16x16x32_bf16(af[m], bf[n], acc[m][n], 0, 0, 0);
    __builtin_amdgcn_s_setprio(0);
    cur++; if (cur == NBUF) cur = 0;
  }

  #pragma unroll
  for (int m = 0; m < MREP; m++)
    #pragma unroll
    for (int n = 0; n < NREP; n++) {
      int r0 = row0A + wm * WTM + m * 16 + ((lane >> 4) << 2);
      int c  = row0B + wn * WTN + n * 16 + (lane & 15);
      #pragma unroll
      for (int q = 0; q < 4; q++) {
        if constexpr (EPI == 0) {
          ((ushort_t*)Cout)[(size_t)(r0 + q) * N + c] = f2bf(acc[m][n][q]);
        } else if constexpr (EPI == 1) {
          size_t idx = (size_t)(r0 + q) * N + c;
          ((float*)Cout)[idx] = acc[m][n][q] + R[idx];
        } else {
          if (c < 33)
            ((float*)Cout)[((size_t)ks * SEQ + r0 + q) * 33 + c] = acc[m][n][q];
        }
      }
    }
}

// ---------------- xp partial reduce (8 K-splits) ----------------
__global__ __launch_bounds__(256) void xp_reduce(const float* __restrict__ part,
                                                 float* __restrict__ xp) {
  int i = blockIdx.x * 256 + threadIdx.x;
  if (i >= SEQ * 33) return;
  float s = 0.f;
  #pragma unroll
  for (int k = 0; k < 8; k++) s += part[(size_t)k * SEQ * 33 + i];
  xp[i] = s;
}

// ---------------- depthwise causal conv + SiLU ----------------
__global__ __launch_bounds__(256) void conv_silu_kernel(const ushort_t* __restrict__ xz_bf,
                                                        const float* __restrict__ cw,
                                                        const float* __restrict__ cb,
                                                        ushort_t* __restrict__ xs_bf) {
  const int t = blockIdx.x;
  const int d0 = threadIdx.x * 8;
  short8 rows[4];
  #pragma unroll
  for (int k = 0; k < 4; k++) {
    int tt = t - 3 + k;
    if (tt >= 0) rows[k] = *(const short8*)&xz_bf[(size_t)tt * (2 * D_INNER) + d0];
    else         rows[k] = (short8)0;
  }
  short8 o8;
  #pragma unroll
  for (int j = 0; j < 8; j++) {
    float4 w = ((const float4*)cw)[d0 + j];
    float acc = cb[d0 + j]
              + bf2f((ushort_t)rows[0][j]) * w.x
              + bf2f((ushort_t)rows[1][j]) * w.y
              + bf2f((ushort_t)rows[2][j]) * w.z
              + bf2f((ushort_t)rows[3][j]) * w.w;
    float sg = 1.f / (1.f + __expf(-acc));
    o8[j] = (short)f2bf(acc * sg);
  }
  *(short8*)&xs_bf[(size_t)t * D_INNER + d0] = o8;
}

// da[n] = g1^(n+1), log-depth
__device__ __forceinline__ void dapow(float g1, float* da) {
  float g2 = g1 * g1, g4 = g2 * g2, g8 = g4 * g4;
  #pragma unroll
  for (int n = 0; n < 16; n++) {
    int e = n + 1;
    float v = (e & 1) ? g1 : 1.f;
    if (e & 2) v *= g2;
    if (e & 4) v *= g4;
    if (e & 8) v *= g8;
    da[n] = v;
  }
}

// ---------------- scan pass1 ----------------
__global__ __launch_bounds__(256) void scan_pass1(const ushort_t* __restrict__ xs_bf,
                                                  const float* __restrict__ xp,
                                                  const float* __restrict__ dt_w,
                                                  const float* __restrict__ dt_b,
                                                  const float* __restrict__ A_log,
                                                  float* __restrict__ Hp,
                                                  float* __restrict__ Sd) {
  int c = blockIdx.x, g = blockIdx.y;
  int d = g * 256 + threadIdx.x;
  __shared__ float Bsh[CLEN][16], drs[CLEN], Ash[16];
  {
    int t = threadIdx.x >> 4, n = threadIdx.x & 15;
    Bsh[t][n] = xp[(size_t)(c * CLEN + t) * 33 + 1 + n];
    if (threadIdx.x < CLEN) drs[threadIdx.x] = xp[(size_t)(c * CLEN + threadIdx.x) * 33];
    else if (threadIdx.x < CLEN + 16) {
      int n2 = threadIdx.x - CLEN;
      Ash[n2] = -__expf(A_log[n2]);
    }
  }
  __syncthreads();
  bool fastA = true;
  #pragma unroll
  for (int n = 0; n < 16; n++) fastA = fastA && (fabsf(Ash[n] + (float)(n + 1)) < 1e-4f * (n + 1));
  float dw = dt_w[d], db = dt_b[d];
  float h[16];
  float S = 0.f;
  #pragma unroll
  for (int n = 0; n < 16; n++) h[n] = 0.f;
  for (int t = 0; t < CLEN; t++) {
    float delta = softplus_f(drs[t] * dw + db);
    S += delta;
    float xv = bf2f(xs_bf[(size_t)(c * CLEN + t) * D_INNER + d]);
    float w = delta * xv;
    float bb[16];
    *(float4*)&bb[0]  = *(const float4*)&Bsh[t][0];
    *(float4*)&bb[4]  = *(const float4*)&Bsh[t][4];
    *(float4*)&bb[8]  = *(const float4*)&Bsh[t][8];
    *(float4*)&bb[12] = *(const float4*)&Bsh[t][12];
    if (fastA) {
      float da[16];
      dapow(__expf(-delta), da);
      #pragma unroll
      for (int n = 0; n < 16; n++) h[n] = da[n] * h[n] + w * bb[n];
    } else {
      #pragma unroll
      for (int n = 0; n < 16; n++) {
        float da = __expf(delta * Ash[n]);
        h[n] = da * h[n] + w * bb[n];
      }
    }
  }
  size_t base = ((size_t)c * D_INNER + d) * 16;
  #pragma unroll
  for (int n = 0; n < 16; n += 4)
    *(float4*)&Hp[base + n] = make_float4(h[n], h[n + 1], h[n + 2], h[n + 3]);
  Sd[(size_t)c * D_INNER + d] = S;
}

// ---------------- scan combine ----------------
__global__ __launch_bounds__(64) void scan_combine(const float* __restrict__ Hp,
                                                   const float* __restrict__ Sd,
                                                   const float* __restrict__ A_log,
                                                   float* __restrict__ Hin) {
  int idx = blockIdx.x * 64 + threadIdx.x;
  int d = idx >> 4, n = idx & 15;
  float An = -__expf(A_log[n]);
  float h = 0.f;
  const size_t stride = (size_t)D_INNER * 16;
  #pragma unroll 8
  for (int c = 0; c < NCHUNK; c++) {
    float S  = Sd[(size_t)c * D_INNER + d];
    float hp = Hp[(size_t)c * stride + idx];
    Hin[(size_t)c * stride + idx] = h;
    h = __expf(An * S) * h + hp;
  }
}

// ---------------- scan pass2 + gating -> y_bf ----------------
__global__ __launch_bounds__(256) void scan_pass2(const ushort_t* __restrict__ xs_bf,
                                                  const float* __restrict__ xp,
                                                  const ushort_t* __restrict__ xz_bf,
                                                  const float* __restrict__ dt_w,
                                                  const float* __restrict__ dt_b,
                                                  const float* __restrict__ A_log,
                                                  const float* __restrict__ Dp,
                                                  const float* __restrict__ Hin,
                                                  ushort_t* __restrict__ y_bf) {
  int c = blockIdx.x, g = blockIdx.y;
  int d = g * 256 + threadIdx.x;
  __shared__ float Bsh[CLEN][16], Csh[CLEN][16], drs[CLEN], Ash[16];
  {
    int t = threadIdx.x >> 4, n = threadIdx.x & 15;
    Bsh[t][n] = xp[(size_t)(c * CLEN + t) * 33 + 1 + n];
    Csh[t][n] = xp[(size_t)(c * CLEN + t) * 33 + 17 + n];
    if (threadIdx.x < CLEN) drs[threadIdx.x] = xp[(size_t)(c * CLEN + threadIdx.x) * 33];
    else if (threadIdx.x < CLEN + 16) {
      int n2 = threadIdx.x - CLEN;
      Ash[n2] = -__expf(A_log[n2]);
    }
  }
  __syncthreads();
  bool fastA = true;
  #pragma unroll
  for (int n = 0; n < 16; n++) fastA = fastA && (fabsf(Ash[n] + (float)(n + 1)) < 1e-4f * (n + 1));
  float dw = dt_w[d], db = dt_b[d], Dd = Dp[d];
  float h[16];
  size_t hbase = ((size_t)c * D_INNER + d) * 16;
  #pragma unroll
  for (int n = 0; n < 16; n += 4)
    *(float4*)&h[n] = *(const float4*)&Hin[hbase + n];
  for (int t = 0; t < CLEN; t++) {
    float delta = softplus_f(drs[t] * dw + db);
    size_t ti = (size_t)(c * CLEN + t);
    float xv = bf2f(xs_bf[ti * D_INNER + d]);
    float w = delta * xv;
    float bb[16], cc[16];
    *(float4*)&bb[0]  = *(const float4*)&Bsh[t][0];
    *(float4*)&bb[4]  = *(const float4*)&Bsh[t][4];
    *(float4*)&bb[8]  = *(const float4*)&Bsh[t][8];
    *(float4*)&bb[12] = *(const float4*)&Bsh[t][12];
    *(float4*)&cc[0]  = *(const float4*)&Csh[t][0];
    *(float4*)&cc[4]  = *(const float4*)&Csh[t][4];
    *(float4*)&cc[8]  = *(const float4*)&Csh[t][8];
    *(float4*)&cc[12] = *(const float4*)&Csh[t][12];
    float y = 0.f;
    if (fastA) {
      float da[16];
      dapow(__expf(-delta), da);
      #pragma unroll
      for (int n = 0; n < 16; n++) {
        h[n] = da[n] * h[n] + w * bb[n];
        y += h[n] * cc[n];
      }
    } else {
      #pragma unroll
      for (int n = 0; n < 16; n++) {
        float da = __expf(delta * Ash[n]);
        h[n] = da * h[n] + w * bb[n];
        y += h[n] * cc[n];
      }
    }
    float z = bf2f(xz_bf[ti * (2 * D_INNER) + D_INNER + d]);
    float sz = z / (1.f + __expf(-z));
    float out = (y + xv * Dd) * sz;
    y_bf[ti * D_INNER + d] = f2bf(out);
  }
}

// ---------------- launch ----------------
extern "C" void kernel_launch(void* const* d_in, const int* in_sizes, int n_in,
                              void* d_out, int out_size, void* d_ws, size_t ws_size,
                              hipStream_t stream) {
  const float* x      = (const float*)d_in[0];
  const float* ln_g   = (const float*)d_in[1];
  const float* ln_b   = (const float*)d_in[2];
  const float* in_w   = (const float*)d_in[3];
  const float* conv_w = (const float*)d_in[4];
  const float* conv_b = (const float*)d_in[5];
  const float* xproj_w= (const float*)d_in[6];
  const float* dt_w   = (const float*)d_in[7];
  const float* dt_b   = (const float*)d_in[8];
  const float* A_log  = (const float*)d_in[9];
  const float* Dp     = (const float*)d_in[10];
  const float* out_w  = (const float*)d_in[11];
  float* out = (float*)d_out;

  char* ws = (char*)d_ws;
  size_t off = 0;
  auto alloc = [&](size_t bytes) { char* p = ws + off; off += (bytes + 255) & ~(size_t)255; return p; };
  ushort_t* xz_bf   = (ushort_t*)alloc((size_t)SEQ * 2 * D_INNER * 2);
  ushort_t* xn_bf   = (ushort_t*)alloc((size_t)SEQ * D_MODEL * 2);
  ushort_t* inw_bf  = (ushort_t*)alloc((size_t)2 * D_INNER * D_MODEL * 2);
  ushort_t* outw_bf = (ushort_t*)alloc((size_t)D_MODEL * D_INNER * 2);
  ushort_t* xpw_bf  = (ushort_t*)alloc((size_t)64 * D_INNER * 2);
  ushort_t* xs_bf   = (ushort_t*)alloc((size_t)SEQ * D_INNER * 2);
  float*    xp_part = (float*)   alloc((size_t)8 * SEQ * 33 * 4);
  float*    xp      = (float*)   alloc((size_t)SEQ * 33 * 4);
  float*    Hp      = (float*)   alloc((size_t)NCHUNK * D_INNER * 16 * 4);
  float*    Hin     = (float*)   alloc((size_t)NCHUNK * D_INNER * 16 * 4);
  float*    Sd      = (float*)   alloc((size_t)NCHUNK * D_INNER * 4);
  ushort_t* y_bf    = (ushort_t*)alloc((size_t)SEQ * D_INNER * 2);
  (void)ws_size;

  const int ncvt = 2 * D_INNER * D_MODEL + D_MODEL * D_INNER + 64 * D_INNER;
  prep_kernel<<<SEQ + (ncvt + 255) / 256, 256, 0, stream>>>(
      x, ln_g, ln_b, in_w, out_w, xproj_w, xn_bf, inw_bf, outw_bf, xpw_bf);
  // in_proj: M=2048 N=4096 K=1024 (NBUF=3, LDS 72KB)
  gemm_pipe<256, 128, D_MODEL, 0, 3, 1><<<dim3(2 * D_INNER / 128, SEQ / 256), 256, 0, stream>>>(
      xn_bf, inw_bf, xz_bf, nullptr, 2 * D_INNER);
  // conv + silu
  conv_silu_kernel<<<SEQ, 256, 0, stream>>>(xz_bf, conv_w, conv_b, xs_bf);
  // x_proj: M=2048 N=64(pad) K=2048, K-split x8 (NBUF=6)
  gemm_pipe<64, 64, D_INNER, 3, 6, 8><<<dim3(8, SEQ / 64), 256, 0, stream>>>(
      xs_bf, xpw_bf, xp_part, nullptr, 64);
  xp_reduce<<<(SEQ * 33 + 255) / 256, 256, 0, stream>>>(xp_part, xp);
  // scan
  scan_pass1<<<dim3(NCHUNK, D_INNER / 256), 256, 0, stream>>>(xs_bf, xp, dt_w, dt_b, A_log, Hp, Sd);
  scan_combine<<<D_INNER * 16 / 64, 64, 0, stream>>>(Hp, Sd, A_log, Hin);
  scan_pass2<<<dim3(NCHUNK, D_INNER / 256), 256, 0, stream>>>(xs_bf, xp, xz_bf, dt_w, dt_b, A_log,
                                                              Dp, Hin, y_bf);
  // out_proj + residual: M=2048 N=1024 K=2048 (NBUF=6, LDS 72KB)
  gemm_pipe<128, 64, D_INNER, 1, 6, 1><<<dim3(D_MODEL / 64, SEQ / 128), 256, 0, stream>>>(
      y_bf, outw_bf, out, x, D_MODEL);
}

// Round 6
// 134.341 us; speedup vs baseline: 1.5575x; 1.0422x over previous
//
#include <hip/hip_runtime.h>
#include <cstdint>
#include <cstddef>

#define D_MODEL 1024
#define D_STATE 16
#define D_CONV  4
#define D_INNER 2048
#define SEQ     2048
#define NCHUNK  128
#define CLEN    16
#define NGRP    8
#define GCH     16
#define LN_EPS  1e-5f

typedef unsigned short ushort_t;
typedef __attribute__((ext_vector_type(8))) short short8;
typedef __attribute__((ext_vector_type(4))) float f32x4;

__device__ __forceinline__ ushort_t f2bf(float x) {
  union { float f; uint32_t u; } v; v.f = x;
  uint32_t r = (v.u + 0x7fffu + ((v.u >> 16) & 1u)) >> 16;
  return (ushort_t)r;
}
__device__ __forceinline__ float bf2f(ushort_t u) {
  union { uint32_t x; float f; } v; v.x = ((uint32_t)u) << 16; return v.f;
}

__device__ __forceinline__ void async16(void* lds, const void* g) {
  __builtin_amdgcn_global_load_lds(
      (const __attribute__((address_space(1))) unsigned int*)g,
      (__attribute__((address_space(3))) unsigned int*)lds, 16, 0, 0);
}

__device__ __forceinline__ float softplus_f(float x) {
  if (x > 20.f) return x;
  if (x < -20.f) return __expf(x);
  return __logf(1.f + __expf(x));
}

// da[n] = g1^(n+1), log-depth
__device__ __forceinline__ void dapow(float g1, float* da) {
  float g2 = g1 * g1, g4 = g2 * g2, g8 = g4 * g4;
  #pragma unroll
  for (int n = 0; n < 16; n++) {
    int e = n + 1;
    float v = (e & 1) ? g1 : 1.f;
    if (e & 2) v *= g2;
    if (e & 4) v *= g4;
    if (e & 8) v *= g8;
    da[n] = v;
  }
}

// ---------------- prep: weight cvt (f32->bf16) + LayerNorm ----------------
__global__ __launch_bounds__(256) void prep_kernel(const float* __restrict__ x,
                                                   const float* __restrict__ g,
                                                   const float* __restrict__ b,
                                                   const float* __restrict__ inw,
                                                   const float* __restrict__ outw,
                                                   const float* __restrict__ xpw,
                                                   ushort_t* __restrict__ xn_bf,
                                                   ushort_t* __restrict__ inw_bf,
                                                   ushort_t* __restrict__ outw_bf,
                                                   ushort_t* __restrict__ xpw_bf) {
  int blk = blockIdx.x;
  if (blk < SEQ) {
    int row = blk;
    const float4* xr = (const float4*)(x + (size_t)row * D_MODEL);
    float4 v = xr[threadIdx.x];
    float s  = v.x + v.y + v.z + v.w;
    float ss = v.x * v.x + v.y * v.y + v.z * v.z + v.w * v.w;
    #pragma unroll
    for (int o = 32; o; o >>= 1) { s += __shfl_down(s, o); ss += __shfl_down(ss, o); }
    __shared__ float sbuf[8], ssbuf[8];
    int wid = threadIdx.x >> 6, lane = threadIdx.x & 63;
    if (lane == 0) { sbuf[wid] = s; ssbuf[wid] = ss; }
    __syncthreads();
    if (threadIdx.x == 0) {
      float t = 0.f, t2 = 0.f;
      for (int i = 0; i < 4; i++) { t += sbuf[i]; t2 += ssbuf[i]; }
      float mu = t / D_MODEL;
      sbuf[4] = mu;
      ssbuf[4] = rsqrtf(t2 / D_MODEL - mu * mu + LN_EPS);
    }
    __syncthreads();
    float mu = sbuf[4], inv = ssbuf[4];
    float4 gv = ((const float4*)g)[threadIdx.x];
    float4 bv = ((const float4*)b)[threadIdx.x];
    ushort_t o4[4];
    o4[0] = f2bf((v.x - mu) * inv * gv.x + bv.x);
    o4[1] = f2bf((v.y - mu) * inv * gv.y + bv.y);
    o4[2] = f2bf((v.z - mu) * inv * gv.z + bv.z);
    o4[3] = f2bf((v.w - mu) * inv * gv.w + bv.w);
    *(ushort4*)&xn_bf[(size_t)row * D_MODEL + threadIdx.x * 4] =
        make_ushort4(o4[0], o4[1], o4[2], o4[3]);
  } else {
    int idx = (blk - SEQ) * 256 + threadIdx.x;
    const int n1 = 2 * D_INNER * D_MODEL;
    const int n2 = D_MODEL * D_INNER;
    const int n3 = 64 * D_INNER;
    if (idx < n1) {
      inw_bf[idx] = f2bf(inw[idx]);
    } else if (idx < n1 + n2) {
      int j = idx - n1;
      outw_bf[j] = f2bf(outw[j]);
    } else if (idx < n1 + n2 + n3) {
      int j = idx - n1 - n2;
      xpw_bf[j] = (j < 33 * D_INNER) ? f2bf(xpw[j]) : (ushort_t)0;
    }
  }
}

// ---------------- unified pipelined MFMA GEMM, NT layout ----------------
template <int BM, int BN, int KDIM, int EPI, int NBUF, int KSPLIT>
__global__ __launch_bounds__(256, 2) void gemm_pipe(const ushort_t* __restrict__ A,
                                                    const ushort_t* __restrict__ B,
                                                    void* __restrict__ Cout,
                                                    const float* __restrict__ R,
                                                    int N) {
  constexpr int KT = KDIM / 32 / KSPLIT;
  constexpr int K2 = KDIM * 2;
  constexpr int IA = BM / 64, IB = BN / 64;
  constexpr int S  = IA + IB;
  constexpr int W  = (NBUF - 2) * S;
  constexpr int WTM = BM / 2, WTN = BN / 2;
  constexpr int MREP = WTM / 16, NREP = WTN / 16;
  __shared__ __align__(16) ushort_t As[NBUF][BM * 32];
  __shared__ __align__(16) ushort_t Bs[NBUF][BN * 32];

  const int nwg = gridDim.x * gridDim.y;
  int bid = blockIdx.y * gridDim.x + blockIdx.x;
  int swz = (bid & 7) * (nwg >> 3) + (bid >> 3);
  int bn = swz % gridDim.x, bm = swz / gridDim.x;
  int ks = 0;
  if constexpr (KSPLIT > 1) { ks = bn; bn = 0; }
  const int tid = threadIdx.x, wid = tid >> 6, lane = tid & 63;
  const int wm = wid >> 1, wn = wid & 1;
  const int row0A = bm * BM, row0B = bn * BN;
  const size_t kbase = (size_t)ks * KT * 64;

  const char* gA[IA];
  const char* gB[IB];
  #pragma unroll
  for (int i = 0; i < IA; i++) {
    int o = i * 4096 + tid * 16;
    int r = o >> 6, src = (o & 63) ^ ((r & 3) << 4);
    gA[i] = (const char*)A + (size_t)(row0A + r) * K2 + src + kbase;
  }
  #pragma unroll
  for (int i = 0; i < IB; i++) {
    int o = i * 4096 + tid * 16;
    int r = o >> 6, src = (o & 63) ^ ((r & 3) << 4);
    gB[i] = (const char*)B + (size_t)(row0B + r) * K2 + src + kbase;
  }
  const int ldsW = wid * 1024;

  auto STAGE = [&](int bb, int kt) {
    int kb = kt * 64;
    #pragma unroll
    for (int i = 0; i < IA; i++)
      async16((char*)&As[bb][0] + i * 4096 + ldsW, gA[i] + kb);
    #pragma unroll
    for (int i = 0; i < IB; i++)
      async16((char*)&Bs[bb][0] + i * 4096 + ldsW, gB[i] + kb);
  };

  #pragma unroll
  for (int p = 0; p < NBUF - 1; p++) STAGE(p, p);

  int offA[MREP], offB[NREP];
  #pragma unroll
  for (int m = 0; m < MREP; m++) {
    int row = wm * WTM + m * 16 + (lane & 15);
    offA[m] = row * 64 + ((((lane >> 4)) ^ (row & 3)) << 4);
  }
  #pragma unroll
  for (int n = 0; n < NREP; n++) {
    int row = wn * WTN + n * 16 + (lane & 15);
    offB[n] = row * 64 + ((((lane >> 4)) ^ (row & 3)) << 4);
  }

  f32x4 acc[MREP][NREP] = {};
  int cur = 0;
  for (int kt = 0; kt < KT; kt++) {
    if (kt < KT - 1) {
      if constexpr (W == 6)       asm volatile("s_waitcnt vmcnt(6)" ::: "memory");
      else if constexpr (W == 8)  asm volatile("s_waitcnt vmcnt(8)" ::: "memory");
      else if constexpr (W == 12) asm volatile("s_waitcnt vmcnt(12)" ::: "memory");
      else                        asm volatile("s_waitcnt vmcnt(0)" ::: "memory");
    } else {
      asm volatile("s_waitcnt vmcnt(0)" ::: "memory");
    }
    __builtin_amdgcn_s_barrier();
    __builtin_amdgcn_sched_barrier(0);
    const char* Ab = (const char*)&As[cur][0];
    const char* Bb = (const char*)&Bs[cur][0];
    short8 af[MREP], bf[NREP];
    #pragma unroll
    for (int m = 0; m < MREP; m++) af[m] = *(const short8*)(Ab + offA[m]);
    #pragma unroll
    for (int n = 0; n < NREP; n++) bf[n] = *(const short8*)(Bb + offB[n]);
    if (kt + NBUF - 1 < KT) {
      int b2 = cur + NBUF - 1; if (b2 >= NBUF) b2 -= NBUF;
      STAGE(b2, kt + NBUF - 1);
    }
    __builtin_amdgcn_s_setprio(1);
    #pragma unroll
    for (int m = 0; m < MREP; m++)
      #pragma unroll
      for (int n = 0; n < NREP; n++)
        acc[m][n] = __builtin_amdgcn_mfma_f32_16x16x32_bf16(af[m], bf[n], acc[m][n], 0, 0, 0);
    __builtin_amdgcn_s_setprio(0);
    cur++; if (cur == NBUF) cur = 0;
  }

  #pragma unroll
  for (int m = 0; m < MREP; m++)
    #pragma unroll
    for (int n = 0; n < NREP; n++) {
      int r0 = row0A + wm * WTM + m * 16 + ((lane >> 4) << 2);
      int c  = row0B + wn * WTN + n * 16 + (lane & 15);
      #pragma unroll
      for (int q = 0; q < 4; q++) {
        if constexpr (EPI == 0) {
          ((ushort_t*)Cout)[(size_t)(r0 + q) * N + c] = f2bf(acc[m][n][q]);
        } else if constexpr (EPI == 1) {
          size_t idx = (size_t)(r0 + q) * N + c;
          ((float*)Cout)[idx] = acc[m][n][q] + R[idx];
        } else {
          if (c < 33)
            ((float*)Cout)[((size_t)ks * SEQ + r0 + q) * 33 + c] = acc[m][n][q];
        }
      }
    }
}

// ---------------- xp partial reduce ----------------
__global__ __launch_bounds__(256) void xp_reduce(const float* __restrict__ part,
                                                 float* __restrict__ xp) {
  int i = blockIdx.x * 256 + threadIdx.x;
  if (i >= SEQ * 33) return;
  float s = 0.f;
  #pragma unroll
  for (int k = 0; k < 8; k++) s += part[(size_t)k * SEQ * 33 + i];
  xp[i] = s;
}

// ---------------- depthwise causal conv + SiLU ----------------
__global__ __launch_bounds__(256) void conv_silu_kernel(const ushort_t* __restrict__ xz_bf,
                                                        const float* __restrict__ cw,
                                                        const float* __restrict__ cb,
                                                        ushort_t* __restrict__ xs_bf) {
  const int t = blockIdx.x;
  const int d0 = threadIdx.x * 8;
  short8 rows[4];
  #pragma unroll
  for (int k = 0; k < 4; k++) {
    int tt = t - 3 + k;
    if (tt >= 0) rows[k] = *(const short8*)&xz_bf[(size_t)tt * (2 * D_INNER) + d0];
    else         rows[k] = (short8)0;
  }
  short8 o8;
  #pragma unroll
  for (int j = 0; j < 8; j++) {
    float4 w = ((const float4*)cw)[d0 + j];
    float acc = cb[d0 + j]
              + bf2f((ushort_t)rows[0][j]) * w.x
              + bf2f((ushort_t)rows[1][j]) * w.y
              + bf2f((ushort_t)rows[2][j]) * w.z
              + bf2f((ushort_t)rows[3][j]) * w.w;
    float sg = 1.f / (1.f + __expf(-acc));
    o8[j] = (short)f2bf(acc * sg);
  }
  *(short8*)&xs_bf[(size_t)t * D_INNER + d0] = o8;
}

// ---------------- scan pass1: 2 d's per thread ----------------
__global__ __launch_bounds__(256) void scan_pass1(const ushort_t* __restrict__ xs_bf,
                                                  const float* __restrict__ xp,
                                                  const float* __restrict__ dt_w,
                                                  const float* __restrict__ dt_b,
                                                  const float* __restrict__ A_log,
                                                  float* __restrict__ Hp,
                                                  float* __restrict__ Sd) {
  int c = blockIdx.x;
  int d0 = blockIdx.y * 512 + threadIdx.x;
  __shared__ float Bsh[CLEN][16], drs[CLEN], Ash[16];
  {
    int t = threadIdx.x >> 4, n = threadIdx.x & 15;
    Bsh[t][n] = xp[(size_t)(c * CLEN + t) * 33 + 1 + n];
    if (threadIdx.x < CLEN) drs[threadIdx.x] = xp[(size_t)(c * CLEN + threadIdx.x) * 33];
    else if (threadIdx.x < CLEN + 16) {
      int n2 = threadIdx.x - CLEN;
      Ash[n2] = -__expf(A_log[n2]);
    }
  }
  __syncthreads();
  bool fastA = true;
  #pragma unroll
  for (int n = 0; n < 16; n++) fastA = fastA && (fabsf(Ash[n] + (float)(n + 1)) < 1e-4f * (n + 1));
  float dw[2] = {dt_w[d0], dt_w[d0 + 256]};
  float db[2] = {dt_b[d0], dt_b[d0 + 256]};
  float h[2][16] = {};
  float S[2] = {0.f, 0.f};
  for (int t = 0; t < CLEN; t++) {
    float bb[16];
    *(float4*)&bb[0]  = *(const float4*)&Bsh[t][0];
    *(float4*)&bb[4]  = *(const float4*)&Bsh[t][4];
    *(float4*)&bb[8]  = *(const float4*)&Bsh[t][8];
    *(float4*)&bb[12] = *(const float4*)&Bsh[t][12];
    float drt = drs[t];
    size_t tb = (size_t)(c * CLEN + t) * D_INNER;
    float xv[2] = {bf2f(xs_bf[tb + d0]), bf2f(xs_bf[tb + d0 + 256])};
    #pragma unroll
    for (int u = 0; u < 2; u++) {
      float delta = softplus_f(drt * dw[u] + db[u]);
      S[u] += delta;
      float w = delta * xv[u];
      if (fastA) {
        float da[16];
        dapow(__expf(-delta), da);
        #pragma unroll
        for (int n = 0; n < 16; n++) h[u][n] = da[n] * h[u][n] + w * bb[n];
      } else {
        #pragma unroll
        for (int n = 0; n < 16; n++) h[u][n] = __expf(delta * Ash[n]) * h[u][n] + w * bb[n];
      }
    }
  }
  #pragma unroll
  for (int u = 0; u < 2; u++) {
    int d = d0 + u * 256;
    size_t base = ((size_t)c * D_INNER + d) * 16;
    #pragma unroll
    for (int n = 0; n < 16; n += 4)
      *(float4*)&Hp[base + n] = make_float4(h[u][n], h[u][n + 1], h[u][n + 2], h[u][n + 3]);
    Sd[(size_t)c * D_INNER + d] = S[u];
  }
}

// ---------------- combine level A: 16-chunk scans within each of 8 groups ----------------
__global__ __launch_bounds__(256) void combineA(const float* __restrict__ Hp,
                                                const float* __restrict__ Sd,
                                                const float* __restrict__ A_log,
                                                float* __restrict__ Hl,
                                                float* __restrict__ Slocp,
                                                float* __restrict__ Hgtot,
                                                float* __restrict__ Sgtot) {
  int g = blockIdx.x;
  int idx = blockIdx.y * 256 + threadIdx.x;   // d*16+n
  int d = idx >> 4, n = idx & 15;
  float An = -__expf(A_log[n]);
  float h = 0.f, S = 0.f;
  const size_t stride = (size_t)D_INNER * 16;
  #pragma unroll 4
  for (int j = 0; j < GCH; j++) {
    int c = g * GCH + j;
    Hl[(size_t)c * stride + idx] = h;
    if (n == 0) Slocp[(size_t)c * D_INNER + d] = S;
    float Sc = Sd[(size_t)c * D_INNER + d];
    float hp = Hp[(size_t)c * stride + idx];
    h = __expf(An * Sc) * h + hp;
    S += Sc;
  }
  Hgtot[(size_t)g * stride + idx] = h;
  if (n == 0) Sgtot[(size_t)g * D_INNER + d] = S;
}

// ---------------- combine level B: 8-long prefix over groups ----------------
__global__ __launch_bounds__(256) void combineB(const float* __restrict__ Hgtot,
                                                const float* __restrict__ Sgtot,
                                                const float* __restrict__ A_log,
                                                float* __restrict__ Ginit) {
  int idx = blockIdx.x * 256 + threadIdx.x;
  int d = idx >> 4, n = idx & 15;
  float An = -__expf(A_log[n]);
  float G = 0.f;
  const size_t stride = (size_t)D_INNER * 16;
  #pragma unroll
  for (int g = 0; g < NGRP; g++) {
    Ginit[(size_t)g * stride + idx] = G;
    G = __expf(An * Sgtot[(size_t)g * D_INNER + d]) * G + Hgtot[(size_t)g * stride + idx];
  }
}

// ---------------- scan pass2 + gating -> y_bf: 2 d's per thread ----------------
__global__ __launch_bounds__(256) void scan_pass2(const ushort_t* __restrict__ xs_bf,
                                                  const float* __restrict__ xp,
                                                  const ushort_t* __restrict__ xz_bf,
                                                  const float* __restrict__ dt_w,
                                                  const float* __restrict__ dt_b,
                                                  const float* __restrict__ A_log,
                                                  const float* __restrict__ Dp,
                                                  const float* __restrict__ Hl,
                                                  const float* __restrict__ Slocp,
                                                  const float* __restrict__ Ginit,
                                                  ushort_t* __restrict__ y_bf) {
  int c = blockIdx.x;
  int d0 = blockIdx.y * 512 + threadIdx.x;
  __shared__ float Bsh[CLEN][16], Csh[CLEN][16], drs[CLEN], Ash[16];
  {
    int t = threadIdx.x >> 4, n = threadIdx.x & 15;
    Bsh[t][n] = xp[(size_t)(c * CLEN + t) * 33 + 1 + n];
    Csh[t][n] = xp[(size_t)(c * CLEN + t) * 33 + 17 + n];
    if (threadIdx.x < CLEN) drs[threadIdx.x] = xp[(size_t)(c * CLEN + threadIdx.x) * 33];
    else if (threadIdx.x < CLEN + 16) {
      int n2 = threadIdx.x - CLEN;
      Ash[n2] = -__expf(A_log[n2]);
    }
  }
  __syncthreads();
  bool fastA = true;
  #pragma unroll
  for (int n = 0; n < 16; n++) fastA = fastA && (fabsf(Ash[n] + (float)(n + 1)) < 1e-4f * (n + 1));
  float dw[2] = {dt_w[d0], dt_w[d0 + 256]};
  float db[2] = {dt_b[d0], dt_b[d0 + 256]};
  float Dd[2] = {Dp[d0], Dp[d0 + 256]};
  int g8 = c >> 4;
  float h[2][16];
  #pragma unroll
  for (int u = 0; u < 2; u++) {
    int d = d0 + u * 256;
    size_t hb = ((size_t)c * D_INNER + d) * 16;
    size_t gb = ((size_t)g8 * D_INNER + d) * 16;
    float Slp = Slocp[(size_t)c * D_INNER + d];
    float hl[16], gi[16];
    #pragma unroll
    for (int n = 0; n < 16; n += 4) {
      *(float4*)&hl[n] = *(const float4*)&Hl[hb + n];
      *(float4*)&gi[n] = *(const float4*)&Ginit[gb + n];
    }
    if (fastA) {
      float pw[16];
      dapow(__expf(-Slp), pw);
      #pragma unroll
      for (int n = 0; n < 16; n++) h[u][n] = hl[n] + pw[n] * gi[n];
    } else {
      #pragma unroll
      for (int n = 0; n < 16; n++) h[u][n] = hl[n] + __expf(Ash[n] * Slp) * gi[n];
    }
  }
  for (int t = 0; t < CLEN; t++) {
    float bb[16], cc[16];
    *(float4*)&bb[0]  = *(const float4*)&Bsh[t][0];
    *(float4*)&bb[4]  = *(const float4*)&Bsh[t][4];
    *(float4*)&bb[8]  = *(const float4*)&Bsh[t][8];
    *(float4*)&bb[12] = *(const float4*)&Bsh[t][12];
    *(float4*)&cc[0]  = *(const float4*)&Csh[t][0];
    *(float4*)&cc[4]  = *(const float4*)&Csh[t][4];
    *(float4*)&cc[8]  = *(const float4*)&Csh[t][8];
    *(float4*)&cc[12] = *(const float4*)&Csh[t][12];
    float drt = drs[t];
    size_t ti = (size_t)(c * CLEN + t);
    float xv[2] = {bf2f(xs_bf[ti * D_INNER + d0]), bf2f(xs_bf[ti * D_INNER + d0 + 256])};
    float zv[2] = {bf2f(xz_bf[ti * (2 * D_INNER) + D_INNER + d0]),
                   bf2f(xz_bf[ti * (2 * D_INNER) + D_INNER + d0 + 256])};
    #pragma unroll
    for (int u = 0; u < 2; u++) {
      float delta = softplus_f(drt * dw[u] + db[u]);
      float w = delta * xv[u];
      float y = 0.f;
      if (fastA) {
        float da[16];
        dapow(__expf(-delta), da);
        #pragma unroll
        for (int n = 0; n < 16; n++) {
          h[u][n] = da[n] * h[u][n] + w * bb[n];
          y += h[u][n] * cc[n];
        }
      } else {
        #pragma unroll
        for (int n = 0; n < 16; n++) {
          h[u][n] = __expf(delta * Ash[n]) * h[u][n] + w * bb[n];
          y += h[u][n] * cc[n];
        }
      }
      float z = zv[u];
      float sz = z / (1.f + __expf(-z));
      float out = (y + xv[u] * Dd[u]) * sz;
      y_bf[ti * D_INNER + d0 + u * 256] = f2bf(out);
    }
  }
}

// ---------------- launch ----------------
extern "C" void kernel_launch(void* const* d_in, const int* in_sizes, int n_in,
                              void* d_out, int out_size, void* d_ws, size_t ws_size,
                              hipStream_t stream) {
  const float* x      = (const float*)d_in[0];
  const float* ln_g   = (const float*)d_in[1];
  const float* ln_b   = (const float*)d_in[2];
  const float* in_w   = (const float*)d_in[3];
  const float* conv_w = (const float*)d_in[4];
  const float* conv_b = (const float*)d_in[5];
  const float* xproj_w= (const float*)d_in[6];
  const float* dt_w   = (const float*)d_in[7];
  const float* dt_b   = (const float*)d_in[8];
  const float* A_log  = (const float*)d_in[9];
  const float* Dp     = (const float*)d_in[10];
  const float* out_w  = (const float*)d_in[11];
  float* out = (float*)d_out;

  char* ws = (char*)d_ws;
  size_t off = 0;
  auto alloc = [&](size_t bytes) { char* p = ws + off; off += (bytes + 255) & ~(size_t)255; return p; };
  ushort_t* xz_bf   = (ushort_t*)alloc((size_t)SEQ * 2 * D_INNER * 2);
  ushort_t* xn_bf   = (ushort_t*)alloc((size_t)SEQ * D_MODEL * 2);
  ushort_t* inw_bf  = (ushort_t*)alloc((size_t)2 * D_INNER * D_MODEL * 2);
  ushort_t* outw_bf = (ushort_t*)alloc((size_t)D_MODEL * D_INNER * 2);
  ushort_t* xpw_bf  = (ushort_t*)alloc((size_t)64 * D_INNER * 2);
  ushort_t* xs_bf   = (ushort_t*)alloc((size_t)SEQ * D_INNER * 2);
  float*    xp_part = (float*)   alloc((size_t)8 * SEQ * 33 * 4);
  float*    xp      = (float*)   alloc((size_t)SEQ * 33 * 4);
  float*    Hp      = (float*)   alloc((size_t)NCHUNK * D_INNER * 16 * 4);
  float*    Hl      = (float*)   alloc((size_t)NCHUNK * D_INNER * 16 * 4);
  float*    Sd      = (float*)   alloc((size_t)NCHUNK * D_INNER * 4);
  float*    Slocp   = (float*)   alloc((size_t)NCHUNK * D_INNER * 4);
  float*    Hgtot   = (float*)   alloc((size_t)NGRP * D_INNER * 16 * 4);
  float*    Sgtot   = (float*)   alloc((size_t)NGRP * D_INNER * 4);
  float*    Ginit   = (float*)   alloc((size_t)NGRP * D_INNER * 16 * 4);
  ushort_t* y_bf    = (ushort_t*)alloc((size_t)SEQ * D_INNER * 2);
  (void)ws_size;

  const int ncvt = 2 * D_INNER * D_MODEL + D_MODEL * D_INNER + 64 * D_INNER;
  prep_kernel<<<SEQ + (ncvt + 255) / 256, 256, 0, stream>>>(
      x, ln_g, ln_b, in_w, out_w, xproj_w, xn_bf, inw_bf, outw_bf, xpw_bf);
  // in_proj: M=2048 N=4096 K=1024 (128x128, NBUF=4, 512 blocks = 2/CU)
  gemm_pipe<128, 128, D_MODEL, 0, 4, 1><<<dim3(2 * D_INNER / 128, SEQ / 128), 256, 0, stream>>>(
      xn_bf, inw_bf, xz_bf, nullptr, 2 * D_INNER);
  conv_silu_kernel<<<SEQ, 256, 0, stream>>>(xz_bf, conv_w, conv_b, xs_bf);
  // x_proj: K-split x8
  gemm_pipe<64, 64, D_INNER, 3, 6, 8><<<dim3(8, SEQ / 64), 256, 0, stream>>>(
      xs_bf, xpw_bf, xp_part, nullptr, 64);
  xp_reduce<<<(SEQ * 33 + 255) / 256, 256, 0, stream>>>(xp_part, xp);
  // scan
  scan_pass1<<<dim3(NCHUNK, D_INNER / 512), 256, 0, stream>>>(xs_bf, xp, dt_w, dt_b, A_log, Hp, Sd);
  combineA<<<dim3(NGRP, D_INNER * 16 / 256), 256, 0, stream>>>(Hp, Sd, A_log, Hl, Slocp, Hgtot, Sgtot);
  combineB<<<D_INNER * 16 / 256, 256, 0, stream>>>(Hgtot, Sgtot, A_log, Ginit);
  scan_pass2<<<dim3(NCHUNK, D_INNER / 512), 256, 0, stream>>>(xs_bf, xp, xz_bf, dt_w, dt_b, A_log,
                                                              Dp, Hl, Slocp, Ginit, y_bf);
  // out_proj + residual: M=2048 N=1024 K=2048 (64x64, NBUF=6, 512 blocks = 2/CU)
  gemm_pipe<64, 64, D_INNER, 1, 6, 1><<<dim3(D_MODEL / 64, SEQ / 64), 256, 0, stream>>>(
      y_bf, outw_bf, out, x, D_MODEL);
}